// Round 22
// baseline (190.793 us; speedup 1.0000x reference)
//
#include <hip/hip_runtime.h>
#include <hip/hip_bf16.h>

namespace {
constexpr int kB  = 16;
constexpr int kN  = 3136;
constexpr int kC  = 256;
constexpr int kH  = 8;     // heads
constexpr int kD  = 32;    // head dim
constexpr int kAG = 49;    // agents
constexpr int kHW = 56;
constexpr int kKV = 512;   // kv projection cols (k 0..255, v 256..511)
constexpr int kSEG = 7;    // n-segments per (b,h); 448 rows each
constexpr int kPART = 33;  // per (b,h,seg,a): l, acc[32]

constexpr int BM = 128, BN = 64, BK = 64;   // BN=64: 2x blocks vs round 19
constexpr int LDK = BK + 8;   // bf16 row stride 72 (144 B)

constexpr int kNT = kN / 256 + 1;  // 13 n-tiles per (b,h)
}

typedef __attribute__((ext_vector_type(8))) short short8;
typedef __attribute__((ext_vector_type(8))) unsigned short ushort8;
typedef __attribute__((ext_vector_type(4))) unsigned short ushort4v;
typedef __attribute__((ext_vector_type(4))) float f32x4;

__device__ __forceinline__ unsigned short f2bf(float f) {
  union { float f; unsigned u; } v; v.f = f;
  unsigned r = (v.u + 0x7FFF + ((v.u >> 16) & 1)) >> 16;  // RNE
  return (unsigned short)r;
}
__device__ __forceinline__ float bf2f(unsigned short u) {
  union { unsigned u; float f; } v; v.u = ((unsigned)u) << 16;
  return v.f;
}

__device__ __forceinline__ float bilin7(const float* __restrict__ tab, int y, int x) {
  // jax.image.resize (7,7)->(56,56) bilinear, half-pixel centers, edge clamp.
  float fy = (y + 0.5f) * 0.125f - 0.5f;
  float fx = (x + 0.5f) * 0.125f - 0.5f;
  float fy0 = floorf(fy), fx0 = floorf(fx);
  float wy = fy - fy0, wx = fx - fx0;
  int y0 = (int)fy0, x0 = (int)fx0;
  int y0c = min(6, max(0, y0)),     x0c = min(6, max(0, x0));
  int y1c = min(6, max(0, y0 + 1)), x1c = min(6, max(0, x0 + 1));
  float v00 = tab[y0c * 7 + x0c], v01 = tab[y0c * 7 + x1c];
  float v10 = tab[y1c * 7 + x0c], v11 = tab[y1c * 7 + x1c];
  float top = v00 + wx * (v01 - v00);
  float bot = v10 + wx * (v11 - v10);
  return top + wy * (bot - top);
}

// ------- weight pre-transpose: Wt(bf16)[n][k] = bf16(W(f32)[k][n]) -------
__global__ __launch_bounds__(256) void wtrans_kernel(
    const float* __restrict__ W, unsigned short* __restrict__ Wt, int K, int N) {
  int idx = blockIdx.x * 256 + threadIdx.x;
  if (idx >= K * N) return;
  int n = idx / K, k = idx - n * K;  // write-coalesced along k
  Wt[idx] = f2bf(W[(size_t)k * N + n]);
}

// ---- bf16-MFMA GEMM (128x64 tile, 4 waves of 64x32): C = A @ Bt^T.
// AMODE 0: A f32 linear [M][K].  AMODE 1: A bf16 head-major [b][h][n][32].
// OMODE 0: C f32 linear [M][N] + bias.  OMODE 1: C bf16 head-major (N=256).
// OMODE 2: C bf16 head-major dual: col<256 -> Cp (k), col>=256 -> Cp2 (v).
template <int AMODE, int OMODE>
__global__ __launch_bounds__(256) void gemm_mixed_kernel(
    const void* __restrict__ Ap, const unsigned short* __restrict__ Bt,
    const float* __restrict__ bias, void* __restrict__ Cp, void* __restrict__ Cp2,
    int M, int Nn, int K) {
  __shared__ unsigned short As[BM * LDK];
  __shared__ unsigned short Bs[BN * LDK];
  const int t = threadIdx.x;

  int tx = blockIdx.x, ty = blockIdx.y;
  {
    int nwg = gridDim.x * gridDim.y;
    if ((nwg & 7) == 0) {
      int bid = ty * gridDim.x + tx;
      int per8 = nwg >> 3;
      int lt = (bid & 7) * per8 + (bid >> 3);
      tx = lt % gridDim.x;
      ty = lt / gridDim.x;
    }
  }
  const int row0 = ty * BM;
  const int col0 = tx * BN;
  const int lane = t & 63;
  const int wid  = t >> 6;
  const int wrow = (wid >> 1) * 64;   // 0 or 64
  const int wcol = (wid & 1) * 32;    // 0 or 32
  const int lr = lane & 15, lg = lane >> 4;

  f32x4 acc[4][2] = {};

  for (int k0 = 0; k0 < K; k0 += BK) {
    __syncthreads();
    if constexpr (AMODE == 1) {
      const unsigned short* A = (const unsigned short*)Ap;
#pragma unroll
      for (int i = 0; i < 4; ++i) {
        int idx = t + i * 256;
        int r = idx >> 3, k8 = (idx & 7) * 8;
        int row = row0 + r;
        int bb = row / kN, nn = row - bb * kN;
        int k = k0 + k8;
        *(ushort8*)&As[r * LDK + k8] = *(const ushort8*)&A[
            (((size_t)bb * kH + (k >> 5)) * kN + nn) * kD + (k & 31)];
      }
    } else {
      const float* A = (const float*)Ap;
#pragma unroll
      for (int i = 0; i < 8; ++i) {
        int idx = t + i * 256;
        int r = idx >> 4, k4 = (idx & 15) * 4;
        float4 f = *(const float4*)&A[(size_t)(row0 + r) * K + k0 + k4];
        unsigned lo = (unsigned)f2bf(f.x) | ((unsigned)f2bf(f.y) << 16);
        unsigned hi = (unsigned)f2bf(f.z) | ((unsigned)f2bf(f.w) << 16);
        *(uint2*)&As[r * LDK + k4] = make_uint2(lo, hi);
      }
    }
#pragma unroll
    for (int i = 0; i < 2; ++i) {
      int idx = t + i * 256;              // 0..511: 64 rows x 8 groups
      int r = idx >> 3, k8 = (idx & 7) * 8;
      *(ushort8*)&Bs[r * LDK + k8] =
          *(const ushort8*)&Bt[(size_t)(col0 + r) * K + k0 + k8];
    }
    __syncthreads();
#pragma unroll
    for (int ks = 0; ks < 2; ++ks) {
      short8 af[4], bf[2];
#pragma unroll
      for (int m = 0; m < 4; ++m)
        af[m] = *(const short8*)&As[(wrow + m * 16 + lr) * LDK + ks * 32 + lg * 8];
#pragma unroll
      for (int n = 0; n < 2; ++n)
        bf[n] = *(const short8*)&Bs[(wcol + n * 16 + lr) * LDK + ks * 32 + lg * 8];
#pragma unroll
      for (int m = 0; m < 4; ++m)
#pragma unroll
        for (int n = 0; n < 2; ++n)
          acc[m][n] = __builtin_amdgcn_mfma_f32_16x16x32_bf16(
              af[m], bf[n], acc[m][n], 0, 0, 0);
    }
  }
#pragma unroll
  for (int m = 0; m < 4; ++m) {
#pragma unroll
    for (int n = 0; n < 2; ++n) {
      int col = col0 + wcol + n * 16 + lr;
      float badd = 0.f;
      if constexpr (OMODE == 0) badd = bias ? bias[col] : 0.f;
#pragma unroll
      for (int j = 0; j < 4; ++j) {
        int row = row0 + wrow + m * 16 + lg * 4 + j;
        if constexpr (OMODE == 0) {
          ((float*)Cp)[(size_t)row * Nn + col] = acc[m][n][j] + badd;
        } else {
          int bb = row / kN, nn = row - bb * kN;
          unsigned short val = f2bf(acc[m][n][j]);
          if constexpr (OMODE == 1) {
            ((unsigned short*)Cp)[(((size_t)bb * kH + (col >> 5)) * kN + nn) * kD
                                  + (col & 31)] = val;
          } else {
            if (col < kC)
              ((unsigned short*)Cp)[(((size_t)bb * kH + (col >> 5)) * kN + nn) * kD
                                    + (col & 31)] = val;
            else {
              int c2 = col - kC;
              ((unsigned short*)Cp2)[(((size_t)bb * kH + (c2 >> 5)) * kN + nn) * kD
                                     + (c2 & 31)] = val;
            }
          }
        }
      }
    }
  }
}

// ---- 8x8 mean pool from head-major qT: agent(f32)[b][a][c], c=h*32+d ----
__global__ __launch_bounds__(256) void pool_kernel(const unsigned short* __restrict__ qT,
                                                   float* __restrict__ agent) {
  int blk = blockIdx.x;
  int b = blk / kAG, a = blk % kAG;
  int ho = a / 7, wo = a % 7;
  int c = threadIdx.x;
  int h = c >> 5, d = c & 31;
  const unsigned short* base = qT + ((size_t)b * kH + h) * kN * kD + d;
  float s = 0.f;
#pragma unroll
  for (int i = 0; i < 8; ++i) {
    int y = ho * 8 + i;
#pragma unroll
    for (int j = 0; j < 8; ++j) {
      int x = wo * 8 + j;
      s += bf2f(base[(size_t)(y * kHW + x) * kD]);
    }
  }
  agent[((size_t)b * kAG + a) * kC + c] = s * (1.f / 64.f);
}

// ------- abias[h][a][n] = bilin(an)[h,a,n] + ah[h,a,y] + aw[h,a,x] (f32) -------
__global__ __launch_bounds__(256) void abias_kernel(
    const float* __restrict__ an_bias, const float* __restrict__ ah_bias,
    const float* __restrict__ aw_bias, float* __restrict__ abias) {
  int ha = blockIdx.x;  // h*kAG + a
  const float* tab = an_bias + ha * 49;
  const float* ahb = ah_bias + ha * kHW;
  const float* awb = aw_bias + ha * kHW;
  for (int n = threadIdx.x; n < kN; n += 256) {
    int y = n / kHW, x = n % kHW;
    abias[(size_t)ha * kN + n] = bilin7(tab, y, x) + ahb[y] + awb[x];
  }
}

// ------- flash agent attention v4: MFMA scores + MFMA PV, head-major k/v -------
__global__ __launch_bounds__(256) void agent_attn_flash4_kernel(
    const float* __restrict__ agent, const unsigned short* __restrict__ kT,
    const unsigned short* __restrict__ vT, const float* __restrict__ abias,
    float* __restrict__ part) {
  const int t = threadIdx.x;
  const int lin = blockIdx.x;
  const int h = lin & 7;           // same-h blocks round-robin -> one XCD
  const int r = lin >> 3;
  const int seg = r % kSEG;
  const int b = r / kSEG;
  const int w = t >> 6, lane = t & 63;
  const int lr = lane & 15, lg = lane >> 4;
  const float scale = 0.17677669529663687f;

  __shared__ char sh[36864];
  unsigned short* agsT = (unsigned short*)sh;                        // [64][40]
  unsigned short* Pa   = (unsigned short*)(sh + 5120) + w * 64 * 40; // per-wave
  unsigned short* Vt   = (unsigned short*)(sh + 25600) + w * 32 * 40;// per-wave
  float* lred = (float*)(sh + 35840);                                // [4][64]

  const unsigned short* kH_ = kT + ((size_t)b * kH + h) * kN * kD;
  const unsigned short* vH_ = vT + ((size_t)b * kH + h) * kN * kD;

  for (int i = t; i < 320; i += 256) *(ushort8*)&agsT[i * 8] = (ushort8)0;
  __syncthreads();
  for (int i = t; i < kAG * 4; i += 256) {
    int a = i >> 2, j = i & 3;
    const float* sp = agent + ((size_t)b * kAG + a) * kC + h * kD + j * 8;
    float4 f0 = *(const float4*)sp, f1 = *(const float4*)(sp + 4);
    ushort8 v;
    v[0] = f2bf(f0.x); v[1] = f2bf(f0.y); v[2] = f2bf(f0.z); v[3] = f2bf(f0.w);
    v[4] = f2bf(f1.x); v[5] = f2bf(f1.y); v[6] = f2bf(f1.z); v[7] = f2bf(f1.w);
    *(ushort8*)&agsT[a * 40 + j * 8] = v;
  }
  __syncthreads();

  float ls[4] = {};
  f32x4 o[4][2] = {};
  const int nchunks = (w < 2) ? 4 : 3;
  for (int ci = 0; ci < nchunks; ++ci) {
    const int chunk = w + 4 * ci;
    const int nb0 = seg * 448 + chunk * 32;
    {
      int n = lane & 31, d0 = (lane >> 5) * 16;
      const unsigned short* vp = vH_ + (size_t)(nb0 + n) * kD + d0;
      ushort8 v0 = *(const ushort8*)vp;
      ushort8 v1 = *(const ushort8*)(vp + 8);
#pragma unroll
      for (int e = 0; e < 8; ++e) Vt[(d0 + e) * 40 + n] = v0[e];
#pragma unroll
      for (int e = 0; e < 8; ++e) Vt[(d0 + 8 + e) * 40 + n] = v1[e];
    }
    short8 af0 = *(const short8*)&kH_[(size_t)(nb0 + lr) * kD + lg * 8];
    short8 af1 = *(const short8*)&kH_[(size_t)(nb0 + 16 + lr) * kD + lg * 8];
    f32x4 c[2][4] = {};
#pragma unroll
    for (int ct = 0; ct < 4; ++ct) {
      short8 bfr = *(const short8*)&agsT[(ct * 16 + lr) * 40 + lg * 8];
      c[0][ct] = __builtin_amdgcn_mfma_f32_16x16x32_bf16(af0, bfr, c[0][ct], 0, 0, 0);
      c[1][ct] = __builtin_amdgcn_mfma_f32_16x16x32_bf16(af1, bfr, c[1][ct], 0, 0, 0);
    }
#pragma unroll
    for (int rt = 0; rt < 2; ++rt) {
#pragma unroll
      for (int ct = 0; ct < 4; ++ct) {
        int a = ct * 16 + lr;
        bool valid = a < kAG;
        float4 ab = {0.f, 0.f, 0.f, 0.f};
        if (valid)
          ab = *(const float4*)&abias[((size_t)(h * kAG + a)) * kN + nb0 + rt * 16 + lg * 4];
        unsigned lo, hi;
        {
          float p0 = valid ? __expf(fmaf(c[rt][ct][0], scale, ab.x)) : 0.f;
          float p1 = valid ? __expf(fmaf(c[rt][ct][1], scale, ab.y)) : 0.f;
          float p2 = valid ? __expf(fmaf(c[rt][ct][2], scale, ab.z)) : 0.f;
          float p3 = valid ? __expf(fmaf(c[rt][ct][3], scale, ab.w)) : 0.f;
          ls[ct] += (p0 + p1) + (p2 + p3);
          lo = (unsigned)f2bf(p0) | ((unsigned)f2bf(p1) << 16);
          hi = (unsigned)f2bf(p2) | ((unsigned)f2bf(p3) << 16);
        }
        *(uint2*)&Pa[a * 40 + rt * 16 + lg * 4] = make_uint2(lo, hi);
      }
    }
    short8 bfv0 = *(const short8*)&Vt[(lr) * 40 + lg * 8];
    short8 bfv1 = *(const short8*)&Vt[(16 + lr) * 40 + lg * 8];
#pragma unroll
    for (int rt = 0; rt < 4; ++rt) {
      short8 afp = *(const short8*)&Pa[(rt * 16 + lr) * 40 + lg * 8];
      o[rt][0] = __builtin_amdgcn_mfma_f32_16x16x32_bf16(afp, bfv0, o[rt][0], 0, 0, 0);
      o[rt][1] = __builtin_amdgcn_mfma_f32_16x16x32_bf16(afp, bfv1, o[rt][1], 0, 0, 0);
    }
  }
#pragma unroll
  for (int ct = 0; ct < 4; ++ct) {
    ls[ct] += __shfl_xor(ls[ct], 16);
    ls[ct] += __shfl_xor(ls[ct], 32);
  }
  __syncthreads();  // all waves done with agsT/Pa/Vt -> overlay reduce bufs
  float* ored = (float*)sh;  // [4][64][33]
  if (lane < 16) {
#pragma unroll
    for (int ct = 0; ct < 4; ++ct) lred[w * 64 + ct * 16 + lane] = ls[ct];
  }
#pragma unroll
  for (int rt = 0; rt < 4; ++rt)
#pragma unroll
    for (int ct2 = 0; ct2 < 2; ++ct2)
#pragma unroll
      for (int reg = 0; reg < 4; ++reg)
        ored[(w * 64 + rt * 16 + lg * 4 + reg) * 33 + ct2 * 16 + lr] =
            o[rt][ct2][reg];
  __syncthreads();
  float* pb = part + (((size_t)(b * kH + h)) * kSEG + seg) * (kAG * kPART);
  if (t < kAG)
    pb[t * kPART] = lred[t] + lred[64 + t] + lred[128 + t] + lred[192 + t];
  for (int i = t; i < kAG * kD; i += 256) {
    int a = i >> 5, d = i & 31;
    float s = ored[a * 33 + d] + ored[(64 + a) * 33 + d]
            + ored[(128 + a) * 33 + d] + ored[(192 + a) * 33 + d];
    pb[a * kPART + 1 + d] = s;
  }
}

// ------- merge the kSEG flash partials -> agent_v[b,h,a,d] (plain sums) -------
__global__ __launch_bounds__(256) void agent_merge_kernel(
    const float* __restrict__ part, float* __restrict__ agent_v) {
  int g = blockIdx.x * 256 + threadIdx.x;  // over nb*kH*kAG*kD
  int d = g & 31;
  int a = (g >> 5) % kAG;
  int bh = g / (kAG * kD);
  const float* pb = part + (((size_t)bh) * kSEG) * (kAG * kPART) + a * kPART;
  float den = 0.f, num = 0.f;
#pragma unroll
  for (int s = 0; s < kSEG; ++s) {
    const float* p = pb + s * kAG * kPART;
    den += p[0];
    num += p[1 + d];
  }
  agent_v[g] = num / den;
}

// ------- qbias(bf16)[h][a][n] = bilin(na) + ha[y,a] + wa[x,a] -------
__global__ __launch_bounds__(256) void qbias_kernel(
    const float* __restrict__ na_bias, const float* __restrict__ ha_bias,
    const float* __restrict__ wa_bias, unsigned short* __restrict__ qbias) {
  int ha = blockIdx.x;  // h*kAG + a
  int h = ha / kAG, a = ha % kAG;
  const float* tab = na_bias + ha * 49;
  for (int n = threadIdx.x; n < kN; n += 256) {
    int y = n / kHW, x = n % kHW;
    qbias[(size_t)ha * kN + n] = f2bf(bilin7(tab, y, x)
        + ha_bias[(h * kHW + y) * kAG + a]
        + wa_bias[(h * kHW + x) * kAG + a]);
  }
}

// --- q-attention v10: head-major q/v (all bulk accesses wave-contiguous) ---
__global__ __launch_bounds__(256) void qattn_v10_kernel(
    unsigned short* __restrict__ qT, const unsigned short* __restrict__ vT,
    const float* __restrict__ agent, const float* __restrict__ agent_v,
    const unsigned short* __restrict__ qbias, const float* __restrict__ dwc_w,
    const float* __restrict__ dwc_b) {
  const int t = threadIdx.x;
  int lin = blockIdx.x + gridDim.x * (blockIdx.y + gridDim.y * blockIdx.z);
  const int h = lin & 7;                     // same-h blocks -> one XCD
  int rest = lin >> 3;
  const int n0 = (rest % kNT) * 256;
  const int b  = rest / kNT;
  const int w = t >> 6, lane = t & 63;
  const int lr = lane & 15, lg = lane >> 4;
  const float scale = 0.17677669529663687f;

  unsigned short* qH_ = qT + ((size_t)b * kH + h) * kN * kD;
  const unsigned short* vH_ = vT + ((size_t)b * kH + h) * kN * kD;

  __shared__ unsigned short agsT[64 * 40];   // [a][d], pad a->64 (5120B)
  __shared__ unsigned short avsT[32 * 72];   // [d][a], pad a->64 (4608B)
  __shared__ unsigned short PW[4][2560];     // per-wave: P [32][72] then OUT [64][36]

  for (int i = t; i < 320; i += 256) *(ushort8*)&agsT[i * 8] = (ushort8)0;
  for (int i = t; i < 288; i += 256) *(ushort8*)&avsT[i * 8] = (ushort8)0;
  __syncthreads();
  for (int i = t; i < kAG * 4; i += 256) {
    int a = i >> 2, j = i & 3;
    const float* sp = agent + ((size_t)b * kAG + a) * kC + h * kD + j * 8;
    float4 f0 = *(const float4*)sp, f1 = *(const float4*)(sp + 4);
    ushort8 v;
    v[0] = f2bf(f0.x); v[1] = f2bf(f0.y); v[2] = f2bf(f0.z); v[3] = f2bf(f0.w);
    v[4] = f2bf(f1.x); v[5] = f2bf(f1.y); v[6] = f2bf(f1.z); v[7] = f2bf(f1.w);
    *(ushort8*)&agsT[a * 40 + j * 8] = v;
  }
  for (int i = t; i < kAG * 8; i += 256) {
    int a = i >> 3, dj = i & 7;
    float4 f = *(const float4*)(agent_v + (((size_t)b * kH + h) * kAG + a) * kD + dj * 4);
    avsT[(dj * 4 + 0) * 72 + a] = f2bf(f.x);
    avsT[(dj * 4 + 1) * 72 + a] = f2bf(f.y);
    avsT[(dj * 4 + 2) * 72 + a] = f2bf(f.z);
    avsT[(dj * 4 + 3) * 72 + a] = f2bf(f.w);
  }
  __syncthreads();

  // ---- MFMA1: scores = q(64x32) @ agentT(32x64) ----
  short8 af[4];
#pragma unroll
  for (int rt = 0; rt < 4; ++rt) {
    int nr = n0 + w * 64 + rt * 16 + lr;
    nr = min(nr, kN - 1);
    af[rt] = *(const short8*)&qH_[(size_t)nr * kD + lg * 8];
  }
  short8 bfr[4];
#pragma unroll
  for (int ct = 0; ct < 4; ++ct)
    bfr[ct] = *(const short8*)&agsT[(ct * 16 + lr) * 40 + lg * 8];
  f32x4 c[4][4] = {};
#pragma unroll
  for (int rt = 0; rt < 4; ++rt)
#pragma unroll
    for (int ct = 0; ct < 4; ++ct)
      c[rt][ct] = __builtin_amdgcn_mfma_f32_16x16x32_bf16(af[rt], bfr[ct],
                                                          c[rt][ct], 0, 0, 0);
  f32x4 lsumv[4] = {};
#pragma unroll
  for (int rt = 0; rt < 4; ++rt) {
#pragma unroll
    for (int ct = 0; ct < 4; ++ct) {
      int col = ct * 16 + lr;
      bool valid = col < kAG;
      int nrow = n0 + w * 64 + rt * 16 + lg * 4;
      nrow = min(nrow, kN - 4);
      float qb[4] = {0.f, 0.f, 0.f, 0.f};
      if (valid) {
        uint2 qw = *(const uint2*)&qbias[((size_t)(h * kAG + col)) * kN + nrow];
        qb[0] = bf2f((unsigned short)(qw.x & 0xffff));
        qb[1] = bf2f((unsigned short)(qw.x >> 16));
        qb[2] = bf2f((unsigned short)(qw.y & 0xffff));
        qb[3] = bf2f((unsigned short)(qw.y >> 16));
      }
#pragma unroll
      for (int reg = 0; reg < 4; ++reg) {
        float pv = valid ? __expf(fmaf(c[rt][ct][reg], scale, qb[reg])) : 0.f;
        c[rt][ct][reg] = pv;
        lsumv[rt][reg] += pv;
      }
    }
  }
#pragma unroll
  for (int rt = 0; rt < 4; ++rt)
#pragma unroll
    for (int j = 0; j < 4; ++j) {
      float v = lsumv[rt][j];
      v += __shfl_xor(v, 1);
      v += __shfl_xor(v, 2);
      v += __shfl_xor(v, 4);
      v += __shfl_xor(v, 8);
      lsumv[rt][j] = v;
    }
  unsigned short* Pw = PW[w];
  short8 bf2v[2][2];
#pragma unroll
  for (int ct2 = 0; ct2 < 2; ++ct2)
#pragma unroll
    for (int ks = 0; ks < 2; ++ks)
      bf2v[ct2][ks] = *(const short8*)&avsT[(ct2 * 16 + lr) * 72 + ks * 32 + lg * 8];
  f32x4 o[4][2] = {};
#pragma unroll
  for (int half = 0; half < 2; ++half) {
#pragma unroll
    for (int rt2 = 0; rt2 < 2; ++rt2)
#pragma unroll
      for (int ct = 0; ct < 4; ++ct)
#pragma unroll
        for (int reg = 0; reg < 4; ++reg)
          Pw[(rt2 * 16 + lg * 4 + reg) * 72 + ct * 16 + lr] =
              f2bf(c[half * 2 + rt2][ct][reg]);
#pragma unroll
    for (int rt2 = 0; rt2 < 2; ++rt2) {
      short8 afp[2];
#pragma unroll
      for (int ks = 0; ks < 2; ++ks)
        afp[ks] = *(const short8*)&Pw[(rt2 * 16 + lr) * 72 + ks * 32 + lg * 8];
      int rt = half * 2 + rt2;
#pragma unroll
      for (int ct2 = 0; ct2 < 2; ++ct2)
#pragma unroll
        for (int ks = 0; ks < 2; ++ks)
          o[rt][ct2] = __builtin_amdgcn_mfma_f32_16x16x32_bf16(
              afp[ks], bf2v[ct2][ks], o[rt][ct2], 0, 0, 0);
    }
  }
#pragma unroll
  for (int rt = 0; rt < 4; ++rt) {
    f32x4 inv;
#pragma unroll
    for (int j = 0; j < 4; ++j) inv[j] = 1.f / lsumv[rt][j];
#pragma unroll
    for (int ct2 = 0; ct2 < 2; ++ct2)
#pragma unroll
      for (int reg = 0; reg < 4; ++reg)
        Pw[(rt * 16 + lg * 4 + reg) * 36 + ct2 * 16 + lr] =
            f2bf(o[rt][ct2][reg] * inv[reg]);
  }
  // ---- dwc tail: thread t owns row n0+t (own-wave region; no barrier) ----
  const int n = n0 + t;
  if (n >= kN) return;
  const unsigned short* orow = &PW[w][(t & 63) * 36];
  float out[kD];
#pragma unroll
  for (int d4 = 0; d4 < 8; ++d4) {
    ushort4v v = *(const ushort4v*)&orow[d4 * 4];
#pragma unroll
    for (int e = 0; e < 4; ++e) out[d4 * 4 + e] = bf2f(v[e]);
  }
  const float* wb = dwc_w + (h * kD) * 9;
  const float* bb = dwc_b + h * kD;
#pragma unroll
  for (int d = 0; d < kD; ++d) out[d] += bb[d];
  const int y = n / kHW, x = n % kHW;
#pragma unroll
  for (int ky = 0; ky < 3; ++ky) {
    int yy = y + ky - 1;
    if (yy < 0 || yy >= kHW) continue;
#pragma unroll
    for (int kx = 0; kx < 3; ++kx) {
      int xx = x + kx - 1;
      if (xx < 0 || xx >= kHW) continue;
      const unsigned short* vp = vH_ + (size_t)(yy * kHW + xx) * kD;
#pragma unroll
      for (int d8 = 0; d8 < 4; ++d8) {
        ushort8 vv = *(const ushort8*)(vp + d8 * 8);
#pragma unroll
        for (int e = 0; e < 8; ++e)
          out[d8 * 8 + e] = fmaf(wb[(d8 * 8 + e) * 9 + ky * 3 + kx],
                                 bf2f(vv[e]), out[d8 * 8 + e]);
      }
    }
  }
  unsigned short* qp = qH_ + (size_t)n * kD;
#pragma unroll
  for (int d8 = 0; d8 < 4; ++d8) {
    ushort8 v;
#pragma unroll
    for (int e = 0; e < 8; ++e) v[e] = f2bf(out[d8 * 8 + e]);
    *(ushort8*)(qp + d8 * 8) = v;
  }
}

extern "C" void kernel_launch(void* const* d_in, const int* in_sizes, int n_in,
                              void* d_out, int out_size, void* d_ws, size_t ws_size,
                              hipStream_t stream) {
  const float* x_f     = (const float*)d_in[0];
  const float* x_t     = (const float*)d_in[1];
  const float* Wq      = (const float*)d_in[2];
  const float* Wkv     = (const float*)d_in[3];
  const float* Wproj   = (const float*)d_in[4];
  const float* bproj   = (const float*)d_in[5];
  const float* dwc_w   = (const float*)d_in[6];
  const float* dwc_b   = (const float*)d_in[7];
  const float* an_bias = (const float*)d_in[8];
  const float* na_bias = (const float*)d_in[9];
  const float* ah_bias = (const float*)d_in[10];
  const float* aw_bias = (const float*)d_in[11];
  const float* ha_bias = (const float*)d_in[12];
  const float* wa_bias = (const float*)d_in[13];
  float* out           = (float*)d_out;  // reference output dtype is float32

  const size_t qbiasN = (size_t)kH * kAG * kN;  // elements per table
  const size_t wtE = (size_t)kC * kC + (size_t)kC * kKV + (size_t)kC * kC;
  const size_t tabB = qbiasN * 2 + qbiasN * 4 + wtE * 2;
  if (ws_size < tabB) return;

  const size_t headE = (size_t)kB * kH * kN * kD;   // elements per head-major tensor
  const size_t qFullB   = headE * 2;                // qT bf16 = 25.7MB
  const size_t agentB   = (size_t)kB * kAG * kC * 4;
  const size_t agentvB  = (size_t)kB * kH * kAG * kD * 4;
  const size_t partB    = (size_t)kB * kH * kSEG * kAG * kPART * 4;
  const size_t fullWsB  = tabB + qFullB + agentB + agentvB + partB;  // ~41MB

  char* p = (char*)d_ws;
  unsigned short* qbias = (unsigned short*)p;  p += qbiasN * 2;
  float* abias = (float*)p;                    p += qbiasN * 4;
  unsigned short* WqT   = (unsigned short*)p;  p += (size_t)kC * kC * 2;
  unsigned short* WkvT  = (unsigned short*)p;  p += (size_t)kC * kKV * 2;
  unsigned short* WprojT= (unsigned short*)p;  p += (size_t)kC * kC * 2;

  qbias_kernel<<<kH * kAG, 256, 0, stream>>>(na_bias, ha_bias, wa_bias, qbias);
  abias_kernel<<<kH * kAG, 256, 0, stream>>>(an_bias, ah_bias, aw_bias, abias);
  wtrans_kernel<<<(kC * kC + 255) / 256, 256, 0, stream>>>(Wq, WqT, kC, kC);
  wtrans_kernel<<<(kC * kKV + 255) / 256, 256, 0, stream>>>(Wkv, WkvT, kC, kKV);
  wtrans_kernel<<<(kC * kC + 255) / 256, 256, 0, stream>>>(Wproj, WprojT, kC, kC);

  if (ws_size >= fullWsB) {
    // ---------- full-batch: kT/vT in d_out (dead before proj writes out) ----------
    unsigned short* qT = (unsigned short*)p;   p += qFullB;
    float* agent  = (float*)p;                 p += agentB;
    float* agentv = (float*)p;                 p += agentvB;
    float* part   = (float*)p;
    unsigned short* kT = (unsigned short*)d_out;
    unsigned short* vT = kT + headE;

    const int M = kB * kN;
    gemm_mixed_kernel<0, 1><<<dim3(kC / BN, M / BM), 256, 0, stream>>>(
        x_f, WqT, nullptr, qT, nullptr, M, kC, kC);
    gemm_mixed_kernel<0, 2><<<dim3(kKV / BN, M / BM), 256, 0, stream>>>(
        x_t, WkvT, nullptr, kT, vT, M, kKV, kC);
    pool_kernel<<<kB * kAG, 256, 0, stream>>>(qT, agent);
    agent_attn_flash4_kernel<<<kB * kH * kSEG, 256, 0, stream>>>(agent, kT, vT,
                                                                 abias, part);
    agent_merge_kernel<<<kB * kAG, 256, 0, stream>>>(part, agentv);
    qattn_v10_kernel<<<dim3(kNT, kH, kB), 256, 0, stream>>>(
        qT, vT, agent, agentv, qbias, dwc_w, dwc_b);
    gemm_mixed_kernel<1, 0><<<dim3(kC / BN, M / BM), 256, 0, stream>>>(
        qT, WprojT, bproj, out, nullptr, M, kC, kC);
    return;
  }

  // ---------- fallback: batch-chunked (kT/vT in ws) ----------
  const size_t perbB = (size_t)kH * kN * kD * 2 * 3   // qT + kT + vT (per batch)
                     + ((size_t)kAG * kC + (size_t)kH * kAG * kD
                        + (size_t)kH * kSEG * kAG * kPART) * 4;
  size_t fit = (ws_size - tabB) / perbB;
  int chunk = (int)(fit < 16 ? fit : 16);
  if (chunk < 1) return;

  const size_t headEc = (size_t)chunk * kH * kN * kD;
  unsigned short* qT = (unsigned short*)p;     p += headEc * 2;
  unsigned short* kT = (unsigned short*)p;     p += headEc * 2;
  unsigned short* vT = (unsigned short*)p;     p += headEc * 2;
  float* agent  = (float*)p;                   p += (size_t)chunk * kAG * kC * 4;
  float* agentv = (float*)p;                   p += (size_t)chunk * kH * kAG * kD * 4;
  float* part   = (float*)p;

  for (int b0 = 0; b0 < kB; b0 += chunk) {
    int nb = (kB - b0) < chunk ? (kB - b0) : chunk;
    const int M = nb * kN;
    const float* xf_c = x_f + (size_t)b0 * kN * kC;
    const float* xt_c = x_t + (size_t)b0 * kN * kC;
    float* out_c = out + (size_t)b0 * kN * kC;

    gemm_mixed_kernel<0, 1><<<dim3(kC / BN, M / BM), 256, 0, stream>>>(
        xf_c, WqT, nullptr, qT, nullptr, M, kC, kC);
    gemm_mixed_kernel<0, 2><<<dim3(kKV / BN, M / BM), 256, 0, stream>>>(
        xt_c, WkvT, nullptr, kT, vT, M, kKV, kC);
    pool_kernel<<<nb * kAG, 256, 0, stream>>>(qT, agent);
    agent_attn_flash4_kernel<<<nb * kH * kSEG, 256, 0, stream>>>(agent, kT, vT,
                                                                 abias, part);
    agent_merge_kernel<<<nb * kAG, 256, 0, stream>>>(part, agentv);
    qattn_v10_kernel<<<dim3(kNT, kH, nb), 256, 0, stream>>>(
        qT, vT, agent, agentv, qbias, dwc_w, dwc_b);
    gemm_mixed_kernel<1, 0><<<dim3(kC / BN, M / BM), 256, 0, stream>>>(
        qT, WprojT, bproj, out_c, nullptr, M, kC, kC);
  }
}

// Round 23
// 183.556 us; speedup vs baseline: 1.0394x; 1.0394x over previous
//
#include <hip/hip_runtime.h>
#include <hip/hip_bf16.h>

namespace {
constexpr int kB  = 16;
constexpr int kN  = 3136;
constexpr int kC  = 256;
constexpr int kH  = 8;     // heads
constexpr int kD  = 32;    // head dim
constexpr int kAG = 49;    // agents
constexpr int kHW = 56;
constexpr int kKV = 512;   // kv projection cols (k 0..255, v 256..511)
constexpr int kSEG = 7;    // n-segments per (b,h); 448 rows each
constexpr int kPART = 33;  // per (b,h,seg,a): l, acc[32]

constexpr int BM = 128, BN = 128, BK = 64;
constexpr int LDK = BK + 8;   // bf16 row stride 72 (144 B)

constexpr int kNT = kN / 256 + 1;  // 13 n-tiles per (b,h)
}

typedef __attribute__((ext_vector_type(8))) short short8;
typedef __attribute__((ext_vector_type(8))) unsigned short ushort8;
typedef __attribute__((ext_vector_type(4))) unsigned short ushort4v;
typedef __attribute__((ext_vector_type(4))) float f32x4;

__device__ __forceinline__ unsigned short f2bf(float f) {
  union { float f; unsigned u; } v; v.f = f;
  unsigned r = (v.u + 0x7FFF + ((v.u >> 16) & 1)) >> 16;  // RNE
  return (unsigned short)r;
}
__device__ __forceinline__ float bf2f(unsigned short u) {
  union { unsigned u; float f; } v; v.u = ((unsigned)u) << 16;
  return v.f;
}

__device__ __forceinline__ float bilin7(const float* __restrict__ tab, int y, int x) {
  // jax.image.resize (7,7)->(56,56) bilinear, half-pixel centers, edge clamp.
  float fy = (y + 0.5f) * 0.125f - 0.5f;
  float fx = (x + 0.5f) * 0.125f - 0.5f;
  float fy0 = floorf(fy), fx0 = floorf(fx);
  float wy = fy - fy0, wx = fx - fx0;
  int y0 = (int)fy0, x0 = (int)fx0;
  int y0c = min(6, max(0, y0)),     x0c = min(6, max(0, x0));
  int y1c = min(6, max(0, y0 + 1)), x1c = min(6, max(0, x0 + 1));
  float v00 = tab[y0c * 7 + x0c], v01 = tab[y0c * 7 + x1c];
  float v10 = tab[y1c * 7 + x0c], v11 = tab[y1c * 7 + x1c];
  float top = v00 + wx * (v01 - v00);
  float bot = v10 + wx * (v11 - v10);
  return top + wy * (bot - top);
}

// ------- fused weight pre-transpose for Wq, Wkv, Wproj -------
__global__ __launch_bounds__(256) void wtrans_all_kernel(
    const float* __restrict__ Wq, const float* __restrict__ Wkv,
    const float* __restrict__ Wproj, unsigned short* __restrict__ WqT,
    unsigned short* __restrict__ WkvT, unsigned short* __restrict__ WprojT) {
  const int E1 = kC * kC, E2 = kC * kKV;
  int idx = blockIdx.x * 256 + threadIdx.x;
  const float* W; unsigned short* Wt; int K, N, local;
  if (idx < E1)            { W = Wq;    Wt = WqT;    K = kC; N = kC;  local = idx; }
  else if (idx < E1 + E2)  { W = Wkv;   Wt = WkvT;   K = kC; N = kKV; local = idx - E1; }
  else if (idx < E1 + E2 + E1) { W = Wproj; Wt = WprojT; K = kC; N = kC; local = idx - E1 - E2; }
  else return;
  int n = local / K, k = local - n * K;
  Wt[local] = f2bf(W[(size_t)k * N + n]);
}

// ------- fused bias tables: qbias(bf16) and abias(f32), one block per ha -------
__global__ __launch_bounds__(256) void tables_kernel(
    const float* __restrict__ na_bias, const float* __restrict__ ha_bias,
    const float* __restrict__ wa_bias, const float* __restrict__ an_bias,
    const float* __restrict__ ah_bias, const float* __restrict__ aw_bias,
    unsigned short* __restrict__ qbias, float* __restrict__ abias) {
  int ha = blockIdx.x;  // h*kAG + a
  int h = ha / kAG, a = ha % kAG;
  const float* ntab = na_bias + ha * 49;
  const float* atab = an_bias + ha * 49;
  const float* ahb = ah_bias + ha * kHW;
  const float* awb = aw_bias + ha * kHW;
  for (int n = threadIdx.x; n < kN; n += 256) {
    int y = n / kHW, x = n % kHW;
    qbias[(size_t)ha * kN + n] = f2bf(bilin7(ntab, y, x)
        + ha_bias[(h * kHW + y) * kAG + a]
        + wa_bias[(h * kHW + x) * kAG + a]);
    abias[(size_t)ha * kN + n] = bilin7(atab, y, x) + ahb[y] + awb[x];
  }
}

// ---- fused q+kv GEMM: one dispatch computes qT = x_f@WqT^T (head-major bf16)
// and kT/vT = x_t@WkvT^T (dual head-major bf16). tx<2 -> q path; else kv.
// Staging/MFMA/epilogue identical to the proven gemm_mixed structure.
__global__ __launch_bounds__(256) void gemm_qkv_kernel(
    const float* __restrict__ xf, const float* __restrict__ xt,
    const unsigned short* __restrict__ WqT, const unsigned short* __restrict__ WkvT,
    unsigned short* __restrict__ qT, unsigned short* __restrict__ kT,
    unsigned short* __restrict__ vT, int M) {
  __shared__ unsigned short As[BM * LDK];
  __shared__ unsigned short Bs[BN * LDK];
  const int t = threadIdx.x;

  int tx = blockIdx.x, ty = blockIdx.y;
  {
    int nwg = gridDim.x * gridDim.y;
    if ((nwg & 7) == 0) {
      int bid = ty * gridDim.x + tx;
      int per8 = nwg >> 3;
      int lt = (bid & 7) * per8 + (bid >> 3);
      tx = lt % gridDim.x;
      ty = lt / gridDim.x;
    }
  }
  const bool isQ = tx < 2;
  const float* A = isQ ? xf : xt;
  const unsigned short* Bt = isQ ? WqT : WkvT;
  const int col0 = (isQ ? tx : tx - 2) * BN;
  const int row0 = ty * BM;
  const int lane = t & 63;
  const int wid  = t >> 6;
  const int wrow = (wid >> 1) * 64;
  const int wcol = (wid & 1) * 64;
  const int lr = lane & 15, lg = lane >> 4;
  const int K = kC;

  f32x4 acc[4][4] = {};

  for (int k0 = 0; k0 < K; k0 += BK) {
    __syncthreads();
#pragma unroll
    for (int i = 0; i < 8; ++i) {
      int idx = t + i * 256;
      int r = idx >> 4, k4 = (idx & 15) * 4;
      float4 f = *(const float4*)&A[(size_t)(row0 + r) * K + k0 + k4];
      unsigned lo = (unsigned)f2bf(f.x) | ((unsigned)f2bf(f.y) << 16);
      unsigned hi = (unsigned)f2bf(f.z) | ((unsigned)f2bf(f.w) << 16);
      *(uint2*)&As[r * LDK + k4] = make_uint2(lo, hi);
    }
#pragma unroll
    for (int i = 0; i < 4; ++i) {
      int idx = t + i * 256;
      int r = idx >> 3, k8 = (idx & 7) * 8;
      *(ushort8*)&Bs[r * LDK + k8] =
          *(const ushort8*)&Bt[(size_t)(col0 + r) * K + k0 + k8];
    }
    __syncthreads();
#pragma unroll
    for (int ks = 0; ks < 2; ++ks) {
      short8 af[4], bf[4];
#pragma unroll
      for (int m = 0; m < 4; ++m)
        af[m] = *(const short8*)&As[(wrow + m * 16 + lr) * LDK + ks * 32 + lg * 8];
#pragma unroll
      for (int n = 0; n < 4; ++n)
        bf[n] = *(const short8*)&Bs[(wcol + n * 16 + lr) * LDK + ks * 32 + lg * 8];
#pragma unroll
      for (int m = 0; m < 4; ++m)
#pragma unroll
        for (int n = 0; n < 4; ++n)
          acc[m][n] = __builtin_amdgcn_mfma_f32_16x16x32_bf16(
              af[m], bf[n], acc[m][n], 0, 0, 0);
    }
  }
#pragma unroll
  for (int m = 0; m < 4; ++m) {
#pragma unroll
    for (int n = 0; n < 4; ++n) {
      int col = col0 + wcol + n * 16 + lr;
#pragma unroll
      for (int j = 0; j < 4; ++j) {
        int row = row0 + wrow + m * 16 + lg * 4 + j;
        int bb = row / kN, nn = row - bb * kN;
        unsigned short val = f2bf(acc[m][n][j]);
        if (isQ) {
          qT[(((size_t)bb * kH + (col >> 5)) * kN + nn) * kD + (col & 31)] = val;
        } else if (col < kC) {
          kT[(((size_t)bb * kH + (col >> 5)) * kN + nn) * kD + (col & 31)] = val;
        } else {
          int c2 = col - kC;
          vT[(((size_t)bb * kH + (c2 >> 5)) * kN + nn) * kD + (c2 & 31)] = val;
        }
      }
    }
  }
}

// ---- proj GEMM: A bf16 head-major -> C f32 linear + bias (proven path) ----
__global__ __launch_bounds__(256) void gemm_proj_kernel(
    const unsigned short* __restrict__ Ap, const unsigned short* __restrict__ Bt,
    const float* __restrict__ bias, float* __restrict__ Cp, int M) {
  __shared__ unsigned short As[BM * LDK];
  __shared__ unsigned short Bs[BN * LDK];
  const int t = threadIdx.x;

  int tx = blockIdx.x, ty = blockIdx.y;
  {
    int nwg = gridDim.x * gridDim.y;
    if ((nwg & 7) == 0) {
      int bid = ty * gridDim.x + tx;
      int per8 = nwg >> 3;
      int lt = (bid & 7) * per8 + (bid >> 3);
      tx = lt % gridDim.x;
      ty = lt / gridDim.x;
    }
  }
  const int row0 = ty * BM;
  const int col0 = tx * BN;
  const int lane = t & 63;
  const int wid  = t >> 6;
  const int wrow = (wid >> 1) * 64;
  const int wcol = (wid & 1) * 64;
  const int lr = lane & 15, lg = lane >> 4;
  const int K = kC, Nn = kC;

  f32x4 acc[4][4] = {};

  for (int k0 = 0; k0 < K; k0 += BK) {
    __syncthreads();
#pragma unroll
    for (int i = 0; i < 4; ++i) {
      int idx = t + i * 256;
      int r = idx >> 3, k8 = (idx & 7) * 8;
      int row = row0 + r;
      int bb = row / kN, nn = row - bb * kN;
      int k = k0 + k8;
      *(ushort8*)&As[r * LDK + k8] = *(const ushort8*)&Ap[
          (((size_t)bb * kH + (k >> 5)) * kN + nn) * kD + (k & 31)];
    }
#pragma unroll
    for (int i = 0; i < 4; ++i) {
      int idx = t + i * 256;
      int r = idx >> 3, k8 = (idx & 7) * 8;
      *(ushort8*)&Bs[r * LDK + k8] =
          *(const ushort8*)&Bt[(size_t)(col0 + r) * K + k0 + k8];
    }
    __syncthreads();
#pragma unroll
    for (int ks = 0; ks < 2; ++ks) {
      short8 af[4], bf[4];
#pragma unroll
      for (int m = 0; m < 4; ++m)
        af[m] = *(const short8*)&As[(wrow + m * 16 + lr) * LDK + ks * 32 + lg * 8];
#pragma unroll
      for (int n = 0; n < 4; ++n)
        bf[n] = *(const short8*)&Bs[(wcol + n * 16 + lr) * LDK + ks * 32 + lg * 8];
#pragma unroll
      for (int m = 0; m < 4; ++m)
#pragma unroll
        for (int n = 0; n < 4; ++n)
          acc[m][n] = __builtin_amdgcn_mfma_f32_16x16x32_bf16(
              af[m], bf[n], acc[m][n], 0, 0, 0);
    }
  }
#pragma unroll
  for (int m = 0; m < 4; ++m) {
#pragma unroll
    for (int n = 0; n < 4; ++n) {
      int col = col0 + wcol + n * 16 + lr;
      float badd = bias[col];
#pragma unroll
      for (int j = 0; j < 4; ++j) {
        int row = row0 + wrow + m * 16 + lg * 4 + j;
        Cp[(size_t)row * Nn + col] = acc[m][n][j] + badd;
      }
    }
  }
}

// ---- 8x8 mean pool from head-major qT: agent(f32)[b][a][c], c=h*32+d ----
__global__ __launch_bounds__(256) void pool_kernel(const unsigned short* __restrict__ qT,
                                                   float* __restrict__ agent) {
  int blk = blockIdx.x;
  int b = blk / kAG, a = blk % kAG;
  int ho = a / 7, wo = a % 7;
  int c = threadIdx.x;
  int h = c >> 5, d = c & 31;
  const unsigned short* base = qT + ((size_t)b * kH + h) * kN * kD + d;
  float s = 0.f;
#pragma unroll
  for (int i = 0; i < 8; ++i) {
    int y = ho * 8 + i;
#pragma unroll
    for (int j = 0; j < 8; ++j) {
      int x = wo * 8 + j;
      s += bf2f(base[(size_t)(y * kHW + x) * kD]);
    }
  }
  agent[((size_t)b * kAG + a) * kC + c] = s * (1.f / 64.f);
}

// ------- flash agent attention v4: MFMA scores + MFMA PV, head-major k/v -------
__global__ __launch_bounds__(256) void agent_attn_flash4_kernel(
    const float* __restrict__ agent, const unsigned short* __restrict__ kT,
    const unsigned short* __restrict__ vT, const float* __restrict__ abias,
    float* __restrict__ part) {
  const int t = threadIdx.x;
  const int lin = blockIdx.x;
  const int h = lin & 7;           // same-h blocks round-robin -> one XCD
  const int r = lin >> 3;
  const int seg = r % kSEG;
  const int b = r / kSEG;
  const int w = t >> 6, lane = t & 63;
  const int lr = lane & 15, lg = lane >> 4;
  const float scale = 0.17677669529663687f;

  __shared__ char sh[36864];
  unsigned short* agsT = (unsigned short*)sh;                        // [64][40]
  unsigned short* Pa   = (unsigned short*)(sh + 5120) + w * 64 * 40; // per-wave
  unsigned short* Vt   = (unsigned short*)(sh + 25600) + w * 32 * 40;// per-wave
  float* lred = (float*)(sh + 35840);                                // [4][64]

  const unsigned short* kH_ = kT + ((size_t)b * kH + h) * kN * kD;
  const unsigned short* vH_ = vT + ((size_t)b * kH + h) * kN * kD;

  for (int i = t; i < 320; i += 256) *(ushort8*)&agsT[i * 8] = (ushort8)0;
  __syncthreads();
  for (int i = t; i < kAG * 4; i += 256) {
    int a = i >> 2, j = i & 3;
    const float* sp = agent + ((size_t)b * kAG + a) * kC + h * kD + j * 8;
    float4 f0 = *(const float4*)sp, f1 = *(const float4*)(sp + 4);
    ushort8 v;
    v[0] = f2bf(f0.x); v[1] = f2bf(f0.y); v[2] = f2bf(f0.z); v[3] = f2bf(f0.w);
    v[4] = f2bf(f1.x); v[5] = f2bf(f1.y); v[6] = f2bf(f1.z); v[7] = f2bf(f1.w);
    *(ushort8*)&agsT[a * 40 + j * 8] = v;
  }
  __syncthreads();

  float ls[4] = {};
  f32x4 o[4][2] = {};
  const int nchunks = (w < 2) ? 4 : 3;
  for (int ci = 0; ci < nchunks; ++ci) {
    const int chunk = w + 4 * ci;
    const int nb0 = seg * 448 + chunk * 32;
    {
      int n = lane & 31, d0 = (lane >> 5) * 16;
      const unsigned short* vp = vH_ + (size_t)(nb0 + n) * kD + d0;
      ushort8 v0 = *(const ushort8*)vp;
      ushort8 v1 = *(const ushort8*)(vp + 8);
#pragma unroll
      for (int e = 0; e < 8; ++e) Vt[(d0 + e) * 40 + n] = v0[e];
#pragma unroll
      for (int e = 0; e < 8; ++e) Vt[(d0 + 8 + e) * 40 + n] = v1[e];
    }
    short8 af0 = *(const short8*)&kH_[(size_t)(nb0 + lr) * kD + lg * 8];
    short8 af1 = *(const short8*)&kH_[(size_t)(nb0 + 16 + lr) * kD + lg * 8];
    f32x4 c[2][4] = {};
#pragma unroll
    for (int ct = 0; ct < 4; ++ct) {
      short8 bfr = *(const short8*)&agsT[(ct * 16 + lr) * 40 + lg * 8];
      c[0][ct] = __builtin_amdgcn_mfma_f32_16x16x32_bf16(af0, bfr, c[0][ct], 0, 0, 0);
      c[1][ct] = __builtin_amdgcn_mfma_f32_16x16x32_bf16(af1, bfr, c[1][ct], 0, 0, 0);
    }
#pragma unroll
    for (int rt = 0; rt < 2; ++rt) {
#pragma unroll
      for (int ct = 0; ct < 4; ++ct) {
        int a = ct * 16 + lr;
        bool valid = a < kAG;
        float4 ab = {0.f, 0.f, 0.f, 0.f};
        if (valid)
          ab = *(const float4*)&abias[((size_t)(h * kAG + a)) * kN + nb0 + rt * 16 + lg * 4];
        unsigned lo, hi;
        {
          float p0 = valid ? __expf(fmaf(c[rt][ct][0], scale, ab.x)) : 0.f;
          float p1 = valid ? __expf(fmaf(c[rt][ct][1], scale, ab.y)) : 0.f;
          float p2 = valid ? __expf(fmaf(c[rt][ct][2], scale, ab.z)) : 0.f;
          float p3 = valid ? __expf(fmaf(c[rt][ct][3], scale, ab.w)) : 0.f;
          ls[ct] += (p0 + p1) + (p2 + p3);
          lo = (unsigned)f2bf(p0) | ((unsigned)f2bf(p1) << 16);
          hi = (unsigned)f2bf(p2) | ((unsigned)f2bf(p3) << 16);
        }
        *(uint2*)&Pa[a * 40 + rt * 16 + lg * 4] = make_uint2(lo, hi);
      }
    }
    short8 bfv0 = *(const short8*)&Vt[(lr) * 40 + lg * 8];
    short8 bfv1 = *(const short8*)&Vt[(16 + lr) * 40 + lg * 8];
#pragma unroll
    for (int rt = 0; rt < 4; ++rt) {
      short8 afp = *(const short8*)&Pa[(rt * 16 + lr) * 40 + lg * 8];
      o[rt][0] = __builtin_amdgcn_mfma_f32_16x16x32_bf16(afp, bfv0, o[rt][0], 0, 0, 0);
      o[rt][1] = __builtin_amdgcn_mfma_f32_16x16x32_bf16(afp, bfv1, o[rt][1], 0, 0, 0);
    }
  }
#pragma unroll
  for (int ct = 0; ct < 4; ++ct) {
    ls[ct] += __shfl_xor(ls[ct], 16);
    ls[ct] += __shfl_xor(ls[ct], 32);
  }
  __syncthreads();  // all waves done with agsT/Pa/Vt -> overlay reduce bufs
  float* ored = (float*)sh;  // [4][64][33]
  if (lane < 16) {
#pragma unroll
    for (int ct = 0; ct < 4; ++ct) lred[w * 64 + ct * 16 + lane] = ls[ct];
  }
#pragma unroll
  for (int rt = 0; rt < 4; ++rt)
#pragma unroll
    for (int ct2 = 0; ct2 < 2; ++ct2)
#pragma unroll
      for (int reg = 0; reg < 4; ++reg)
        ored[(w * 64 + rt * 16 + lg * 4 + reg) * 33 + ct2 * 16 + lr] =
            o[rt][ct2][reg];
  __syncthreads();
  float* pb = part + (((size_t)(b * kH + h)) * kSEG + seg) * (kAG * kPART);
  if (t < kAG)
    pb[t * kPART] = lred[t] + lred[64 + t] + lred[128 + t] + lred[192 + t];
  for (int i = t; i < kAG * kD; i += 256) {
    int a = i >> 5, d = i & 31;
    float s = ored[a * 33 + d] + ored[(64 + a) * 33 + d]
            + ored[(128 + a) * 33 + d] + ored[(192 + a) * 33 + d];
    pb[a * kPART + 1 + d] = s;
  }
}

// ------- merge the kSEG flash partials -> agent_v[b,h,a,d] (plain sums) -------
__global__ __launch_bounds__(256) void agent_merge_kernel(
    const float* __restrict__ part, float* __restrict__ agent_v) {
  int g = blockIdx.x * 256 + threadIdx.x;  // over nb*kH*kAG*kD
  int d = g & 31;
  int a = (g >> 5) % kAG;
  int bh = g / (kAG * kD);
  const float* pb = part + (((size_t)bh) * kSEG) * (kAG * kPART) + a * kPART;
  float den = 0.f, num = 0.f;
#pragma unroll
  for (int s = 0; s < kSEG; ++s) {
    const float* p = pb + s * kAG * kPART;
    den += p[0];
    num += p[1 + d];
  }
  agent_v[g] = num / den;
}

// --- q-attention v10: head-major q/v (all bulk accesses wave-contiguous) ---
__global__ __launch_bounds__(256) void qattn_v10_kernel(
    unsigned short* __restrict__ qT, const unsigned short* __restrict__ vT,
    const float* __restrict__ agent, const float* __restrict__ agent_v,
    const unsigned short* __restrict__ qbias, const float* __restrict__ dwc_w,
    const float* __restrict__ dwc_b) {
  const int t = threadIdx.x;
  int lin = blockIdx.x + gridDim.x * (blockIdx.y + gridDim.y * blockIdx.z);
  const int h = lin & 7;                     // same-h blocks -> one XCD
  int rest = lin >> 3;
  const int n0 = (rest % kNT) * 256;
  const int b  = rest / kNT;
  const int w = t >> 6, lane = t & 63;
  const int lr = lane & 15, lg = lane >> 4;
  const float scale = 0.17677669529663687f;

  unsigned short* qH_ = qT + ((size_t)b * kH + h) * kN * kD;
  const unsigned short* vH_ = vT + ((size_t)b * kH + h) * kN * kD;

  __shared__ unsigned short agsT[64 * 40];   // [a][d], pad a->64 (5120B)
  __shared__ unsigned short avsT[32 * 72];   // [d][a], pad a->64 (4608B)
  __shared__ unsigned short PW[4][2560];     // per-wave: P [32][72] then OUT [64][36]

  for (int i = t; i < 320; i += 256) *(ushort8*)&agsT[i * 8] = (ushort8)0;
  for (int i = t; i < 288; i += 256) *(ushort8*)&avsT[i * 8] = (ushort8)0;
  __syncthreads();
  for (int i = t; i < kAG * 4; i += 256) {
    int a = i >> 2, j = i & 3;
    const float* sp = agent + ((size_t)b * kAG + a) * kC + h * kD + j * 8;
    float4 f0 = *(const float4*)sp, f1 = *(const float4*)(sp + 4);
    ushort8 v;
    v[0] = f2bf(f0.x); v[1] = f2bf(f0.y); v[2] = f2bf(f0.z); v[3] = f2bf(f0.w);
    v[4] = f2bf(f1.x); v[5] = f2bf(f1.y); v[6] = f2bf(f1.z); v[7] = f2bf(f1.w);
    *(ushort8*)&agsT[a * 40 + j * 8] = v;
  }
  for (int i = t; i < kAG * 8; i += 256) {
    int a = i >> 3, dj = i & 7;
    float4 f = *(const float4*)(agent_v + (((size_t)b * kH + h) * kAG + a) * kD + dj * 4);
    avsT[(dj * 4 + 0) * 72 + a] = f2bf(f.x);
    avsT[(dj * 4 + 1) * 72 + a] = f2bf(f.y);
    avsT[(dj * 4 + 2) * 72 + a] = f2bf(f.z);
    avsT[(dj * 4 + 3) * 72 + a] = f2bf(f.w);
  }
  __syncthreads();

  // ---- MFMA1: scores = q(64x32) @ agentT(32x64) ----
  short8 af[4];
#pragma unroll
  for (int rt = 0; rt < 4; ++rt) {
    int nr = n0 + w * 64 + rt * 16 + lr;
    nr = min(nr, kN - 1);
    af[rt] = *(const short8*)&qH_[(size_t)nr * kD + lg * 8];
  }
  short8 bfr[4];
#pragma unroll
  for (int ct = 0; ct < 4; ++ct)
    bfr[ct] = *(const short8*)&agsT[(ct * 16 + lr) * 40 + lg * 8];
  f32x4 c[4][4] = {};
#pragma unroll
  for (int rt = 0; rt < 4; ++rt)
#pragma unroll
    for (int ct = 0; ct < 4; ++ct)
      c[rt][ct] = __builtin_amdgcn_mfma_f32_16x16x32_bf16(af[rt], bfr[ct],
                                                          c[rt][ct], 0, 0, 0);
  f32x4 lsumv[4] = {};
#pragma unroll
  for (int rt = 0; rt < 4; ++rt) {
#pragma unroll
    for (int ct = 0; ct < 4; ++ct) {
      int col = ct * 16 + lr;
      bool valid = col < kAG;
      int nrow = n0 + w * 64 + rt * 16 + lg * 4;
      nrow = min(nrow, kN - 4);
      float qb[4] = {0.f, 0.f, 0.f, 0.f};
      if (valid) {
        uint2 qw = *(const uint2*)&qbias[((size_t)(h * kAG + col)) * kN + nrow];
        qb[0] = bf2f((unsigned short)(qw.x & 0xffff));
        qb[1] = bf2f((unsigned short)(qw.x >> 16));
        qb[2] = bf2f((unsigned short)(qw.y & 0xffff));
        qb[3] = bf2f((unsigned short)(qw.y >> 16));
      }
#pragma unroll
      for (int reg = 0; reg < 4; ++reg) {
        float pv = valid ? __expf(fmaf(c[rt][ct][reg], scale, qb[reg])) : 0.f;
        c[rt][ct][reg] = pv;
        lsumv[rt][reg] += pv;
      }
    }
  }
#pragma unroll
  for (int rt = 0; rt < 4; ++rt)
#pragma unroll
    for (int j = 0; j < 4; ++j) {
      float v = lsumv[rt][j];
      v += __shfl_xor(v, 1);
      v += __shfl_xor(v, 2);
      v += __shfl_xor(v, 4);
      v += __shfl_xor(v, 8);
      lsumv[rt][j] = v;
    }
  unsigned short* Pw = PW[w];
  short8 bf2v[2][2];
#pragma unroll
  for (int ct2 = 0; ct2 < 2; ++ct2)
#pragma unroll
    for (int ks = 0; ks < 2; ++ks)
      bf2v[ct2][ks] = *(const short8*)&avsT[(ct2 * 16 + lr) * 72 + ks * 32 + lg * 8];
  f32x4 o[4][2] = {};
#pragma unroll
  for (int half = 0; half < 2; ++half) {
#pragma unroll
    for (int rt2 = 0; rt2 < 2; ++rt2)
#pragma unroll
      for (int ct = 0; ct < 4; ++ct)
#pragma unroll
        for (int reg = 0; reg < 4; ++reg)
          Pw[(rt2 * 16 + lg * 4 + reg) * 72 + ct * 16 + lr] =
              f2bf(c[half * 2 + rt2][ct][reg]);
#pragma unroll
    for (int rt2 = 0; rt2 < 2; ++rt2) {
      short8 afp[2];
#pragma unroll
      for (int ks = 0; ks < 2; ++ks)
        afp[ks] = *(const short8*)&Pw[(rt2 * 16 + lr) * 72 + ks * 32 + lg * 8];
      int rt = half * 2 + rt2;
#pragma unroll
      for (int ct2 = 0; ct2 < 2; ++ct2)
#pragma unroll
        for (int ks = 0; ks < 2; ++ks)
          o[rt][ct2] = __builtin_amdgcn_mfma_f32_16x16x32_bf16(
              afp[ks], bf2v[ct2][ks], o[rt][ct2], 0, 0, 0);
    }
  }
#pragma unroll
  for (int rt = 0; rt < 4; ++rt) {
    f32x4 inv;
#pragma unroll
    for (int j = 0; j < 4; ++j) inv[j] = 1.f / lsumv[rt][j];
#pragma unroll
    for (int ct2 = 0; ct2 < 2; ++ct2)
#pragma unroll
      for (int reg = 0; reg < 4; ++reg)
        Pw[(rt * 16 + lg * 4 + reg) * 36 + ct2 * 16 + lr] =
            f2bf(o[rt][ct2][reg] * inv[reg]);
  }
  // ---- dwc tail: thread t owns row n0+t (own-wave region; no barrier) ----
  const int n = n0 + t;
  if (n >= kN) return;
  const unsigned short* orow = &PW[w][(t & 63) * 36];
  float out[kD];
#pragma unroll
  for (int d4 = 0; d4 < 8; ++d4) {
    ushort4v v = *(const ushort4v*)&orow[d4 * 4];
#pragma unroll
    for (int e = 0; e < 4; ++e) out[d4 * 4 + e] = bf2f(v[e]);
  }
  const float* wb = dwc_w + (h * kD) * 9;
  const float* bb = dwc_b + h * kD;
#pragma unroll
  for (int d = 0; d < kD; ++d) out[d] += bb[d];
  const int y = n / kHW, x = n % kHW;
#pragma unroll
  for (int ky = 0; ky < 3; ++ky) {
    int yy = y + ky - 1;
    if (yy < 0 || yy >= kHW) continue;
#pragma unroll
    for (int kx = 0; kx < 3; ++kx) {
      int xx = x + kx - 1;
      if (xx < 0 || xx >= kHW) continue;
      const unsigned short* vp = vH_ + (size_t)(yy * kHW + xx) * kD;
#pragma unroll
      for (int d8 = 0; d8 < 4; ++d8) {
        ushort8 vv = *(const ushort8*)(vp + d8 * 8);
#pragma unroll
        for (int e = 0; e < 8; ++e)
          out[d8 * 8 + e] = fmaf(wb[(d8 * 8 + e) * 9 + ky * 3 + kx],
                                 bf2f(vv[e]), out[d8 * 8 + e]);
      }
    }
  }
  unsigned short* qp = qH_ + (size_t)n * kD;
#pragma unroll
  for (int d8 = 0; d8 < 4; ++d8) {
    ushort8 v;
#pragma unroll
    for (int e = 0; e < 8; ++e) v[e] = f2bf(out[d8 * 8 + e]);
    *(ushort8*)(qp + d8 * 8) = v;
  }
}

extern "C" void kernel_launch(void* const* d_in, const int* in_sizes, int n_in,
                              void* d_out, int out_size, void* d_ws, size_t ws_size,
                              hipStream_t stream) {
  const float* x_f     = (const float*)d_in[0];
  const float* x_t     = (const float*)d_in[1];
  const float* Wq      = (const float*)d_in[2];
  const float* Wkv     = (const float*)d_in[3];
  const float* Wproj   = (const float*)d_in[4];
  const float* bproj   = (const float*)d_in[5];
  const float* dwc_w   = (const float*)d_in[6];
  const float* dwc_b   = (const float*)d_in[7];
  const float* an_bias = (const float*)d_in[8];
  const float* na_bias = (const float*)d_in[9];
  const float* ah_bias = (const float*)d_in[10];
  const float* aw_bias = (const float*)d_in[11];
  const float* ha_bias = (const float*)d_in[12];
  const float* wa_bias = (const float*)d_in[13];
  float* out           = (float*)d_out;  // reference output dtype is float32

  const size_t qbiasN = (size_t)kH * kAG * kN;  // elements per table
  const size_t wtE = (size_t)kC * kC + (size_t)kC * kKV + (size_t)kC * kC;
  const size_t tabB = qbiasN * 2 + qbiasN * 4 + wtE * 2;
  if (ws_size < tabB) return;

  const size_t headE = (size_t)kB * kH * kN * kD;   // elements per head-major tensor
  const size_t qFullB   = headE * 2;                // qT bf16 = 25.7MB
  const size_t agentB   = (size_t)kB * kAG * kC * 4;
  const size_t agentvB  = (size_t)kB * kH * kAG * kD * 4;
  const size_t partB    = (size_t)kB * kH * kSEG * kAG * kPART * 4;
  const size_t fullWsB  = tabB + qFullB + agentB + agentvB + partB;  // ~41MB

  char* p = (char*)d_ws;
  unsigned short* qbias = (unsigned short*)p;  p += qbiasN * 2;
  float* abias = (float*)p;                    p += qbiasN * 4;
  unsigned short* WqT   = (unsigned short*)p;  p += (size_t)kC * kC * 2;
  unsigned short* WkvT  = (unsigned short*)p;  p += (size_t)kC * kKV * 2;
  unsigned short* WprojT= (unsigned short*)p;  p += (size_t)kC * kC * 2;

  tables_kernel<<<kH * kAG, 256, 0, stream>>>(na_bias, ha_bias, wa_bias,
                                              an_bias, ah_bias, aw_bias,
                                              qbias, abias);
  wtrans_all_kernel<<<(int)((wtE + 255) / 256), 256, 0, stream>>>(
      Wq, Wkv, Wproj, WqT, WkvT, WprojT);

  if (ws_size >= fullWsB) {
    // ---------- full-batch: kT/vT in d_out (dead before proj writes out) ----------
    unsigned short* qT = (unsigned short*)p;   p += qFullB;
    float* agent  = (float*)p;                 p += agentB;
    float* agentv = (float*)p;                 p += agentvB;
    float* part   = (float*)p;
    unsigned short* kT = (unsigned short*)d_out;
    unsigned short* vT = kT + headE;

    const int M = kB * kN;
    gemm_qkv_kernel<<<dim3(6, M / BM), 256, 0, stream>>>(
        x_f, x_t, WqT, WkvT, qT, kT, vT, M);
    pool_kernel<<<kB * kAG, 256, 0, stream>>>(qT, agent);
    agent_attn_flash4_kernel<<<kB * kH * kSEG, 256, 0, stream>>>(agent, kT, vT,
                                                                 abias, part);
    agent_merge_kernel<<<kB * kAG, 256, 0, stream>>>(part, agentv);
    qattn_v10_kernel<<<dim3(kNT, kH, kB), 256, 0, stream>>>(
        qT, vT, agent, agentv, qbias, dwc_w, dwc_b);
    gemm_proj_kernel<<<dim3(kC / BN, M / BM), 256, 0, stream>>>(
        qT, WprojT, bproj, out, M);
    return;
  }

  // ---------- fallback: batch-chunked (kT/vT in ws) ----------
  const size_t perbB = (size_t)kH * kN * kD * 2 * 3   // qT + kT + vT (per batch)
                     + ((size_t)kAG * kC + (size_t)kH * kAG * kD
                        + (size_t)kH * kSEG * kAG * kPART) * 4;
  size_t fit = (ws_size - tabB) / perbB;
  int chunk = (int)(fit < 16 ? fit : 16);
  if (chunk < 1) return;

  const size_t headEc = (size_t)chunk * kH * kN * kD;
  unsigned short* qT = (unsigned short*)p;     p += headEc * 2;
  unsigned short* kT = (unsigned short*)p;     p += headEc * 2;
  unsigned short* vT = (unsigned short*)p;     p += headEc * 2;
  float* agent  = (float*)p;                   p += (size_t)chunk * kAG * kC * 4;
  float* agentv = (float*)p;                   p += (size_t)chunk * kH * kAG * kD * 4;
  float* part   = (float*)p;

  for (int b0 = 0; b0 < kB; b0 += chunk) {
    int nb = (kB - b0) < chunk ? (kB - b0) : chunk;
    const int M = nb * kN;
    const float* xf_c = x_f + (size_t)b0 * kN * kC;
    const float* xt_c = x_t + (size_t)b0 * kN * kC;
    float* out_c = out + (size_t)b0 * kN * kC;

    gemm_qkv_kernel<<<dim3(6, M / BM), 256, 0, stream>>>(
        xf_c, xt_c, WqT, WkvT, qT, kT, vT, M);
    pool_kernel<<<nb * kAG, 256, 0, stream>>>(qT, agent);
    agent_attn_flash4_kernel<<<nb * kH * kSEG, 256, 0, stream>>>(agent, kT, vT,
                                                                 abias, part);
    agent_merge_kernel<<<nb * kAG, 256, 0, stream>>>(part, agentv);
    qattn_v10_kernel<<<dim3(kNT, kH, nb), 256, 0, stream>>>(
        qT, vT, agent, agentv, qbias, dwc_w, dwc_b);
    gemm_proj_kernel<<<dim3(kC / BN, M / BM), 256, 0, stream>>>(
        qT, WprojT, bproj, out_c, M);
  }
}

// Round 24
// 180.640 us; speedup vs baseline: 1.0562x; 1.0161x over previous
//
#include <hip/hip_runtime.h>
#include <hip/hip_bf16.h>

namespace {
constexpr int kB  = 16;
constexpr int kN  = 3136;
constexpr int kC  = 256;
constexpr int kH  = 8;     // heads
constexpr int kD  = 32;    // head dim
constexpr int kAG = 49;    // agents
constexpr int kHW = 56;
constexpr int kKV = 512;   // kv projection cols (k 0..255, v 256..511)
constexpr int kSEG = 7;    // n-segments per (b,h); 448 rows each
constexpr int kPART = 33;  // per (b,h,seg,a): l, acc[32]

constexpr int BM = 128, BN = 128, BK = 64;
constexpr int LDK = BK + 8;   // bf16 row stride 72 (144 B)

constexpr int kNT = kN / 256 + 1;  // 13 n-tiles per (b,h)
}

typedef __attribute__((ext_vector_type(8))) short short8;
typedef __attribute__((ext_vector_type(8))) unsigned short ushort8;
typedef __attribute__((ext_vector_type(4))) unsigned short ushort4v;
typedef __attribute__((ext_vector_type(4))) float f32x4;

__device__ __forceinline__ unsigned short f2bf(float f) {
  union { float f; unsigned u; } v; v.f = f;
  unsigned r = (v.u + 0x7FFF + ((v.u >> 16) & 1)) >> 16;  // RNE
  return (unsigned short)r;
}
__device__ __forceinline__ float bf2f(unsigned short u) {
  union { unsigned u; float f; } v; v.u = ((unsigned)u) << 16;
  return v.f;
}

__device__ __forceinline__ float bilin7(const float* __restrict__ tab, int y, int x) {
  // jax.image.resize (7,7)->(56,56) bilinear, half-pixel centers, edge clamp.
  float fy = (y + 0.5f) * 0.125f - 0.5f;
  float fx = (x + 0.5f) * 0.125f - 0.5f;
  float fy0 = floorf(fy), fx0 = floorf(fx);
  float wy = fy - fy0, wx = fx - fx0;
  int y0 = (int)fy0, x0 = (int)fx0;
  int y0c = min(6, max(0, y0)),     x0c = min(6, max(0, x0));
  int y1c = min(6, max(0, y0 + 1)), x1c = min(6, max(0, x0 + 1));
  float v00 = tab[y0c * 7 + x0c], v01 = tab[y0c * 7 + x1c];
  float v10 = tab[y1c * 7 + x0c], v11 = tab[y1c * 7 + x1c];
  float top = v00 + wx * (v01 - v00);
  float bot = v10 + wx * (v11 - v10);
  return top + wy * (bot - top);
}

// ------- fused setup: bias tables (blocks 0..391) + weight transpose (rest) -------
__global__ __launch_bounds__(256) void setup_kernel(
    const float* __restrict__ na_bias, const float* __restrict__ ha_bias,
    const float* __restrict__ wa_bias, const float* __restrict__ an_bias,
    const float* __restrict__ ah_bias, const float* __restrict__ aw_bias,
    unsigned short* __restrict__ qbias, float* __restrict__ abias,
    const float* __restrict__ Wq, const float* __restrict__ Wkv,
    const float* __restrict__ Wproj, unsigned short* __restrict__ WqT,
    unsigned short* __restrict__ WkvT, unsigned short* __restrict__ WprojT) {
  const int nTab = kH * kAG;  // 392 table blocks
  if (blockIdx.x < nTab) {
    int ha = blockIdx.x;  // h*kAG + a
    int h = ha / kAG, a = ha % kAG;
    const float* ntab = na_bias + ha * 49;
    const float* atab = an_bias + ha * 49;
    const float* ahb = ah_bias + ha * kHW;
    const float* awb = aw_bias + ha * kHW;
    for (int n = threadIdx.x; n < kN; n += 256) {
      int y = n / kHW, x = n % kHW;
      qbias[(size_t)ha * kN + n] = f2bf(bilin7(ntab, y, x)
          + ha_bias[(h * kHW + y) * kAG + a]
          + wa_bias[(h * kHW + x) * kAG + a]);
      abias[(size_t)ha * kN + n] = bilin7(atab, y, x) + ahb[y] + awb[x];
    }
    return;
  }
  const int E1 = kC * kC, E2 = kC * kKV;
  int idx = (blockIdx.x - nTab) * 256 + threadIdx.x;
  const float* W; unsigned short* Wt; int K, N, local;
  if (idx < E1)                { W = Wq;    Wt = WqT;    K = kC; N = kC;  local = idx; }
  else if (idx < E1 + E2)      { W = Wkv;   Wt = WkvT;   K = kC; N = kKV; local = idx - E1; }
  else if (idx < E1 + E2 + E1) { W = Wproj; Wt = WprojT; K = kC; N = kC;  local = idx - E1 - E2; }
  else return;
  int n = local / K, k = local - n * K;
  Wt[local] = f2bf(W[(size_t)k * N + n]);
}

// ---- fused q+kv GEMM: one dispatch computes qT = x_f@WqT^T (head-major bf16)
// and kT/vT = x_t@WkvT^T (dual head-major bf16). tx<2 -> q path; else kv.
__global__ __launch_bounds__(256) void gemm_qkv_kernel(
    const float* __restrict__ xf, const float* __restrict__ xt,
    const unsigned short* __restrict__ WqT, const unsigned short* __restrict__ WkvT,
    unsigned short* __restrict__ qT, unsigned short* __restrict__ kT,
    unsigned short* __restrict__ vT, int M) {
  __shared__ unsigned short As[BM * LDK];
  __shared__ unsigned short Bs[BN * LDK];
  const int t = threadIdx.x;

  int tx = blockIdx.x, ty = blockIdx.y;
  {
    int nwg = gridDim.x * gridDim.y;
    if ((nwg & 7) == 0) {
      int bid = ty * gridDim.x + tx;
      int per8 = nwg >> 3;
      int lt = (bid & 7) * per8 + (bid >> 3);
      tx = lt % gridDim.x;
      ty = lt / gridDim.x;
    }
  }
  const bool isQ = tx < 2;
  const float* A = isQ ? xf : xt;
  const unsigned short* Bt = isQ ? WqT : WkvT;
  const int col0 = (isQ ? tx : tx - 2) * BN;
  const int row0 = ty * BM;
  const int lane = t & 63;
  const int wid  = t >> 6;
  const int wrow = (wid >> 1) * 64;
  const int wcol = (wid & 1) * 64;
  const int lr = lane & 15, lg = lane >> 4;
  const int K = kC;

  f32x4 acc[4][4] = {};

  for (int k0 = 0; k0 < K; k0 += BK) {
    __syncthreads();
#pragma unroll
    for (int i = 0; i < 8; ++i) {
      int idx = t + i * 256;
      int r = idx >> 4, k4 = (idx & 15) * 4;
      float4 f = *(const float4*)&A[(size_t)(row0 + r) * K + k0 + k4];
      unsigned lo = (unsigned)f2bf(f.x) | ((unsigned)f2bf(f.y) << 16);
      unsigned hi = (unsigned)f2bf(f.z) | ((unsigned)f2bf(f.w) << 16);
      *(uint2*)&As[r * LDK + k4] = make_uint2(lo, hi);
    }
#pragma unroll
    for (int i = 0; i < 4; ++i) {
      int idx = t + i * 256;
      int r = idx >> 3, k8 = (idx & 7) * 8;
      *(ushort8*)&Bs[r * LDK + k8] =
          *(const ushort8*)&Bt[(size_t)(col0 + r) * K + k0 + k8];
    }
    __syncthreads();
#pragma unroll
    for (int ks = 0; ks < 2; ++ks) {
      short8 af[4], bf[4];
#pragma unroll
      for (int m = 0; m < 4; ++m)
        af[m] = *(const short8*)&As[(wrow + m * 16 + lr) * LDK + ks * 32 + lg * 8];
#pragma unroll
      for (int n = 0; n < 4; ++n)
        bf[n] = *(const short8*)&Bs[(wcol + n * 16 + lr) * LDK + ks * 32 + lg * 8];
#pragma unroll
      for (int m = 0; m < 4; ++m)
#pragma unroll
        for (int n = 0; n < 4; ++n)
          acc[m][n] = __builtin_amdgcn_mfma_f32_16x16x32_bf16(
              af[m], bf[n], acc[m][n], 0, 0, 0);
    }
  }
#pragma unroll
  for (int m = 0; m < 4; ++m) {
#pragma unroll
    for (int n = 0; n < 4; ++n) {
      int col = col0 + wcol + n * 16 + lr;
#pragma unroll
      for (int j = 0; j < 4; ++j) {
        int row = row0 + wrow + m * 16 + lg * 4 + j;
        int bb = row / kN, nn = row - bb * kN;
        unsigned short val = f2bf(acc[m][n][j]);
        if (isQ) {
          qT[(((size_t)bb * kH + (col >> 5)) * kN + nn) * kD + (col & 31)] = val;
        } else if (col < kC) {
          kT[(((size_t)bb * kH + (col >> 5)) * kN + nn) * kD + (col & 31)] = val;
        } else {
          int c2 = col - kC;
          vT[(((size_t)bb * kH + (c2 >> 5)) * kN + nn) * kD + (c2 & 31)] = val;
        }
      }
    }
  }
}

// ---- proj GEMM: A bf16 head-major -> C f32 linear + bias ----
__global__ __launch_bounds__(256) void gemm_proj_kernel(
    const unsigned short* __restrict__ Ap, const unsigned short* __restrict__ Bt,
    const float* __restrict__ bias, float* __restrict__ Cp, int M) {
  __shared__ unsigned short As[BM * LDK];
  __shared__ unsigned short Bs[BN * LDK];
  const int t = threadIdx.x;

  int tx = blockIdx.x, ty = blockIdx.y;
  {
    int nwg = gridDim.x * gridDim.y;
    if ((nwg & 7) == 0) {
      int bid = ty * gridDim.x + tx;
      int per8 = nwg >> 3;
      int lt = (bid & 7) * per8 + (bid >> 3);
      tx = lt % gridDim.x;
      ty = lt / gridDim.x;
    }
  }
  const int row0 = ty * BM;
  const int col0 = tx * BN;
  const int lane = t & 63;
  const int wid  = t >> 6;
  const int wrow = (wid >> 1) * 64;
  const int wcol = (wid & 1) * 64;
  const int lr = lane & 15, lg = lane >> 4;
  const int K = kC, Nn = kC;

  f32x4 acc[4][4] = {};

  for (int k0 = 0; k0 < K; k0 += BK) {
    __syncthreads();
#pragma unroll
    for (int i = 0; i < 4; ++i) {
      int idx = t + i * 256;
      int r = idx >> 3, k8 = (idx & 7) * 8;
      int row = row0 + r;
      int bb = row / kN, nn = row - bb * kN;
      int k = k0 + k8;
      *(ushort8*)&As[r * LDK + k8] = *(const ushort8*)&Ap[
          (((size_t)bb * kH + (k >> 5)) * kN + nn) * kD + (k & 31)];
    }
#pragma unroll
    for (int i = 0; i < 4; ++i) {
      int idx = t + i * 256;
      int r = idx >> 3, k8 = (idx & 7) * 8;
      *(ushort8*)&Bs[r * LDK + k8] =
          *(const ushort8*)&Bt[(size_t)(col0 + r) * K + k0 + k8];
    }
    __syncthreads();
#pragma unroll
    for (int ks = 0; ks < 2; ++ks) {
      short8 af[4], bf[4];
#pragma unroll
      for (int m = 0; m < 4; ++m)
        af[m] = *(const short8*)&As[(wrow + m * 16 + lr) * LDK + ks * 32 + lg * 8];
#pragma unroll
      for (int n = 0; n < 4; ++n)
        bf[n] = *(const short8*)&Bs[(wcol + n * 16 + lr) * LDK + ks * 32 + lg * 8];
#pragma unroll
      for (int m = 0; m < 4; ++m)
#pragma unroll
        for (int n = 0; n < 4; ++n)
          acc[m][n] = __builtin_amdgcn_mfma_f32_16x16x32_bf16(
              af[m], bf[n], acc[m][n], 0, 0, 0);
    }
  }
#pragma unroll
  for (int m = 0; m < 4; ++m) {
#pragma unroll
    for (int n = 0; n < 4; ++n) {
      int col = col0 + wcol + n * 16 + lr;
      float badd = bias[col];
#pragma unroll
      for (int j = 0; j < 4; ++j) {
        int row = row0 + wrow + m * 16 + lg * 4 + j;
        Cp[(size_t)row * Nn + col] = acc[m][n][j] + badd;
      }
    }
  }
}

// ---- 8x8 mean pool from head-major qT: agent(f32)[b][a][c], c=h*32+d ----
__global__ __launch_bounds__(256) void pool_kernel(const unsigned short* __restrict__ qT,
                                                   float* __restrict__ agent) {
  int blk = blockIdx.x;
  int b = blk / kAG, a = blk % kAG;
  int ho = a / 7, wo = a % 7;
  int c = threadIdx.x;
  int h = c >> 5, d = c & 31;
  const unsigned short* base = qT + ((size_t)b * kH + h) * kN * kD + d;
  float s = 0.f;
#pragma unroll
  for (int i = 0; i < 8; ++i) {
    int y = ho * 8 + i;
#pragma unroll
    for (int j = 0; j < 8; ++j) {
      int x = wo * 8 + j;
      s += bf2f(base[(size_t)(y * kHW + x) * kD]);
    }
  }
  agent[((size_t)b * kAG + a) * kC + c] = s * (1.f / 64.f);
}

// ------- flash agent attention v4: MFMA scores + MFMA PV, head-major k/v -------
__global__ __launch_bounds__(256) void agent_attn_flash4_kernel(
    const float* __restrict__ agent, const unsigned short* __restrict__ kT,
    const unsigned short* __restrict__ vT, const float* __restrict__ abias,
    float* __restrict__ part) {
  const int t = threadIdx.x;
  const int lin = blockIdx.x;
  const int h = lin & 7;           // same-h blocks round-robin -> one XCD
  const int r = lin >> 3;
  const int seg = r % kSEG;
  const int b = r / kSEG;
  const int w = t >> 6, lane = t & 63;
  const int lr = lane & 15, lg = lane >> 4;
  const float scale = 0.17677669529663687f;

  __shared__ char sh[36864];
  unsigned short* agsT = (unsigned short*)sh;                        // [64][40]
  unsigned short* Pa   = (unsigned short*)(sh + 5120) + w * 64 * 40; // per-wave
  unsigned short* Vt   = (unsigned short*)(sh + 25600) + w * 32 * 40;// per-wave
  float* lred = (float*)(sh + 35840);                                // [4][64]

  const unsigned short* kH_ = kT + ((size_t)b * kH + h) * kN * kD;
  const unsigned short* vH_ = vT + ((size_t)b * kH + h) * kN * kD;

  for (int i = t; i < 320; i += 256) *(ushort8*)&agsT[i * 8] = (ushort8)0;
  __syncthreads();
  for (int i = t; i < kAG * 4; i += 256) {
    int a = i >> 2, j = i & 3;
    const float* sp = agent + ((size_t)b * kAG + a) * kC + h * kD + j * 8;
    float4 f0 = *(const float4*)sp, f1 = *(const float4*)(sp + 4);
    ushort8 v;
    v[0] = f2bf(f0.x); v[1] = f2bf(f0.y); v[2] = f2bf(f0.z); v[3] = f2bf(f0.w);
    v[4] = f2bf(f1.x); v[5] = f2bf(f1.y); v[6] = f2bf(f1.z); v[7] = f2bf(f1.w);
    *(ushort8*)&agsT[a * 40 + j * 8] = v;
  }
  __syncthreads();

  float ls[4] = {};
  f32x4 o[4][2] = {};
  const int nchunks = (w < 2) ? 4 : 3;
  for (int ci = 0; ci < nchunks; ++ci) {
    const int chunk = w + 4 * ci;
    const int nb0 = seg * 448 + chunk * 32;
    {
      int n = lane & 31, d0 = (lane >> 5) * 16;
      const unsigned short* vp = vH_ + (size_t)(nb0 + n) * kD + d0;
      ushort8 v0 = *(const ushort8*)vp;
      ushort8 v1 = *(const ushort8*)(vp + 8);
#pragma unroll
      for (int e = 0; e < 8; ++e) Vt[(d0 + e) * 40 + n] = v0[e];
#pragma unroll
      for (int e = 0; e < 8; ++e) Vt[(d0 + 8 + e) * 40 + n] = v1[e];
    }
    short8 af0 = *(const short8*)&kH_[(size_t)(nb0 + lr) * kD + lg * 8];
    short8 af1 = *(const short8*)&kH_[(size_t)(nb0 + 16 + lr) * kD + lg * 8];
    f32x4 c[2][4] = {};
#pragma unroll
    for (int ct = 0; ct < 4; ++ct) {
      short8 bfr = *(const short8*)&agsT[(ct * 16 + lr) * 40 + lg * 8];
      c[0][ct] = __builtin_amdgcn_mfma_f32_16x16x32_bf16(af0, bfr, c[0][ct], 0, 0, 0);
      c[1][ct] = __builtin_amdgcn_mfma_f32_16x16x32_bf16(af1, bfr, c[1][ct], 0, 0, 0);
    }
#pragma unroll
    for (int rt = 0; rt < 2; ++rt) {
#pragma unroll
      for (int ct = 0; ct < 4; ++ct) {
        int a = ct * 16 + lr;
        bool valid = a < kAG;
        float4 ab = {0.f, 0.f, 0.f, 0.f};
        if (valid)
          ab = *(const float4*)&abias[((size_t)(h * kAG + a)) * kN + nb0 + rt * 16 + lg * 4];
        unsigned lo, hi;
        {
          float p0 = valid ? __expf(fmaf(c[rt][ct][0], scale, ab.x)) : 0.f;
          float p1 = valid ? __expf(fmaf(c[rt][ct][1], scale, ab.y)) : 0.f;
          float p2 = valid ? __expf(fmaf(c[rt][ct][2], scale, ab.z)) : 0.f;
          float p3 = valid ? __expf(fmaf(c[rt][ct][3], scale, ab.w)) : 0.f;
          ls[ct] += (p0 + p1) + (p2 + p3);
          lo = (unsigned)f2bf(p0) | ((unsigned)f2bf(p1) << 16);
          hi = (unsigned)f2bf(p2) | ((unsigned)f2bf(p3) << 16);
        }
        *(uint2*)&Pa[a * 40 + rt * 16 + lg * 4] = make_uint2(lo, hi);
      }
    }
    short8 bfv0 = *(const short8*)&Vt[(lr) * 40 + lg * 8];
    short8 bfv1 = *(const short8*)&Vt[(16 + lr) * 40 + lg * 8];
#pragma unroll
    for (int rt = 0; rt < 4; ++rt) {
      short8 afp = *(const short8*)&Pa[(rt * 16 + lr) * 40 + lg * 8];
      o[rt][0] = __builtin_amdgcn_mfma_f32_16x16x32_bf16(afp, bfv0, o[rt][0], 0, 0, 0);
      o[rt][1] = __builtin_amdgcn_mfma_f32_16x16x32_bf16(afp, bfv1, o[rt][1], 0, 0, 0);
    }
  }
#pragma unroll
  for (int ct = 0; ct < 4; ++ct) {
    ls[ct] += __shfl_xor(ls[ct], 16);
    ls[ct] += __shfl_xor(ls[ct], 32);
  }
  __syncthreads();  // all waves done with agsT/Pa/Vt -> overlay reduce bufs
  float* ored = (float*)sh;  // [4][64][33]
  if (lane < 16) {
#pragma unroll
    for (int ct = 0; ct < 4; ++ct) lred[w * 64 + ct * 16 + lane] = ls[ct];
  }
#pragma unroll
  for (int rt = 0; rt < 4; ++rt)
#pragma unroll
    for (int ct2 = 0; ct2 < 2; ++ct2)
#pragma unroll
      for (int reg = 0; reg < 4; ++reg)
        ored[(w * 64 + rt * 16 + lg * 4 + reg) * 33 + ct2 * 16 + lr] =
            o[rt][ct2][reg];
  __syncthreads();
  float* pb = part + (((size_t)(b * kH + h)) * kSEG + seg) * (kAG * kPART);
  if (t < kAG)
    pb[t * kPART] = lred[t] + lred[64 + t] + lred[128 + t] + lred[192 + t];
  for (int i = t; i < kAG * kD; i += 256) {
    int a = i >> 5, d = i & 31;
    float s = ored[a * 33 + d] + ored[(64 + a) * 33 + d]
            + ored[(128 + a) * 33 + d] + ored[(192 + a) * 33 + d];
    pb[a * kPART + 1 + d] = s;
  }
}

// ------- merge the kSEG flash partials -> agent_v[b,h,a,d] (plain sums) -------
__global__ __launch_bounds__(256) void agent_merge_kernel(
    const float* __restrict__ part, float* __restrict__ agent_v) {
  int g = blockIdx.x * 256 + threadIdx.x;  // over nb*kH*kAG*kD
  int d = g & 31;
  int a = (g >> 5) % kAG;
  int bh = g / (kAG * kD);
  const float* pb = part + (((size_t)bh) * kSEG) * (kAG * kPART) + a * kPART;
  float den = 0.f, num = 0.f;
#pragma unroll
  for (int s = 0; s < kSEG; ++s) {
    const float* p = pb + s * kAG * kPART;
    den += p[0];
    num += p[1 + d];
  }
  agent_v[g] = num / den;
}

// --- q-attention v10: head-major q/v (all bulk accesses wave-contiguous) ---
__global__ __launch_bounds__(256) void qattn_v10_kernel(
    unsigned short* __restrict__ qT, const unsigned short* __restrict__ vT,
    const float* __restrict__ agent, const float* __restrict__ agent_v,
    const unsigned short* __restrict__ qbias, const float* __restrict__ dwc_w,
    const float* __restrict__ dwc_b) {
  const int t = threadIdx.x;
  int lin = blockIdx.x + gridDim.x * (blockIdx.y + gridDim.y * blockIdx.z);
  const int h = lin & 7;                     // same-h blocks -> one XCD
  int rest = lin >> 3;
  const int n0 = (rest % kNT) * 256;
  const int b  = rest / kNT;
  const int w = t >> 6, lane = t & 63;
  const int lr = lane & 15, lg = lane >> 4;
  const float scale = 0.17677669529663687f;

  unsigned short* qH_ = qT + ((size_t)b * kH + h) * kN * kD;
  const unsigned short* vH_ = vT + ((size_t)b * kH + h) * kN * kD;

  __shared__ unsigned short agsT[64 * 40];   // [a][d], pad a->64 (5120B)
  __shared__ unsigned short avsT[32 * 72];   // [d][a], pad a->64 (4608B)
  __shared__ unsigned short PW[4][2560];     // per-wave: P [32][72] then OUT [64][36]

  for (int i = t; i < 320; i += 256) *(ushort8*)&agsT[i * 8] = (ushort8)0;
  for (int i = t; i < 288; i += 256) *(ushort8*)&avsT[i * 8] = (ushort8)0;
  __syncthreads();
  for (int i = t; i < kAG * 4; i += 256) {
    int a = i >> 2, j = i & 3;
    const float* sp = agent + ((size_t)b * kAG + a) * kC + h * kD + j * 8;
    float4 f0 = *(const float4*)sp, f1 = *(const float4*)(sp + 4);
    ushort8 v;
    v[0] = f2bf(f0.x); v[1] = f2bf(f0.y); v[2] = f2bf(f0.z); v[3] = f2bf(f0.w);
    v[4] = f2bf(f1.x); v[5] = f2bf(f1.y); v[6] = f2bf(f1.z); v[7] = f2bf(f1.w);
    *(ushort8*)&agsT[a * 40 + j * 8] = v;
  }
  for (int i = t; i < kAG * 8; i += 256) {
    int a = i >> 3, dj = i & 7;
    float4 f = *(const float4*)(agent_v + (((size_t)b * kH + h) * kAG + a) * kD + dj * 4);
    avsT[(dj * 4 + 0) * 72 + a] = f2bf(f.x);
    avsT[(dj * 4 + 1) * 72 + a] = f2bf(f.y);
    avsT[(dj * 4 + 2) * 72 + a] = f2bf(f.z);
    avsT[(dj * 4 + 3) * 72 + a] = f2bf(f.w);
  }
  __syncthreads();

  // ---- MFMA1: scores = q(64x32) @ agentT(32x64) ----
  short8 af[4];
#pragma unroll
  for (int rt = 0; rt < 4; ++rt) {
    int nr = n0 + w * 64 + rt * 16 + lr;
    nr = min(nr, kN - 1);
    af[rt] = *(const short8*)&qH_[(size_t)nr * kD + lg * 8];
  }
  short8 bfr[4];
#pragma unroll
  for (int ct = 0; ct < 4; ++ct)
    bfr[ct] = *(const short8*)&agsT[(ct * 16 + lr) * 40 + lg * 8];
  f32x4 c[4][4] = {};
#pragma unroll
  for (int rt = 0; rt < 4; ++rt)
#pragma unroll
    for (int ct = 0; ct < 4; ++ct)
      c[rt][ct] = __builtin_amdgcn_mfma_f32_16x16x32_bf16(af[rt], bfr[ct],
                                                          c[rt][ct], 0, 0, 0);
  f32x4 lsumv[4] = {};
#pragma unroll
  for (int rt = 0; rt < 4; ++rt) {
#pragma unroll
    for (int ct = 0; ct < 4; ++ct) {
      int col = ct * 16 + lr;
      bool valid = col < kAG;
      int nrow = n0 + w * 64 + rt * 16 + lg * 4;
      nrow = min(nrow, kN - 4);
      float qb[4] = {0.f, 0.f, 0.f, 0.f};
      if (valid) {
        uint2 qw = *(const uint2*)&qbias[((size_t)(h * kAG + col)) * kN + nrow];
        qb[0] = bf2f((unsigned short)(qw.x & 0xffff));
        qb[1] = bf2f((unsigned short)(qw.x >> 16));
        qb[2] = bf2f((unsigned short)(qw.y & 0xffff));
        qb[3] = bf2f((unsigned short)(qw.y >> 16));
      }
#pragma unroll
      for (int reg = 0; reg < 4; ++reg) {
        float pv = valid ? __expf(fmaf(c[rt][ct][reg], scale, qb[reg])) : 0.f;
        c[rt][ct][reg] = pv;
        lsumv[rt][reg] += pv;
      }
    }
  }
#pragma unroll
  for (int rt = 0; rt < 4; ++rt)
#pragma unroll
    for (int j = 0; j < 4; ++j) {
      float v = lsumv[rt][j];
      v += __shfl_xor(v, 1);
      v += __shfl_xor(v, 2);
      v += __shfl_xor(v, 4);
      v += __shfl_xor(v, 8);
      lsumv[rt][j] = v;
    }
  unsigned short* Pw = PW[w];
  short8 bf2v[2][2];
#pragma unroll
  for (int ct2 = 0; ct2 < 2; ++ct2)
#pragma unroll
    for (int ks = 0; ks < 2; ++ks)
      bf2v[ct2][ks] = *(const short8*)&avsT[(ct2 * 16 + lr) * 72 + ks * 32 + lg * 8];
  f32x4 o[4][2] = {};
#pragma unroll
  for (int half = 0; half < 2; ++half) {
#pragma unroll
    for (int rt2 = 0; rt2 < 2; ++rt2)
#pragma unroll
      for (int ct = 0; ct < 4; ++ct)
#pragma unroll
        for (int reg = 0; reg < 4; ++reg)
          Pw[(rt2 * 16 + lg * 4 + reg) * 72 + ct * 16 + lr] =
              f2bf(c[half * 2 + rt2][ct][reg]);
#pragma unroll
    for (int rt2 = 0; rt2 < 2; ++rt2) {
      short8 afp[2];
#pragma unroll
      for (int ks = 0; ks < 2; ++ks)
        afp[ks] = *(const short8*)&Pw[(rt2 * 16 + lr) * 72 + ks * 32 + lg * 8];
      int rt = half * 2 + rt2;
#pragma unroll
      for (int ct2 = 0; ct2 < 2; ++ct2)
#pragma unroll
        for (int ks = 0; ks < 2; ++ks)
          o[rt][ct2] = __builtin_amdgcn_mfma_f32_16x16x32_bf16(
              afp[ks], bf2v[ct2][ks], o[rt][ct2], 0, 0, 0);
    }
  }
#pragma unroll
  for (int rt = 0; rt < 4; ++rt) {
    f32x4 inv;
#pragma unroll
    for (int j = 0; j < 4; ++j) inv[j] = 1.f / lsumv[rt][j];
#pragma unroll
    for (int ct2 = 0; ct2 < 2; ++ct2)
#pragma unroll
      for (int reg = 0; reg < 4; ++reg)
        Pw[(rt * 16 + lg * 4 + reg) * 36 + ct2 * 16 + lr] =
            f2bf(o[rt][ct2][reg] * inv[reg]);
  }
  // ---- dwc tail: thread t owns row n0+t (own-wave region; no barrier) ----
  const int n = n0 + t;
  if (n >= kN) return;
  const unsigned short* orow = &PW[w][(t & 63) * 36];
  float out[kD];
#pragma unroll
  for (int d4 = 0; d4 < 8; ++d4) {
    ushort4v v = *(const ushort4v*)&orow[d4 * 4];
#pragma unroll
    for (int e = 0; e < 4; ++e) out[d4 * 4 + e] = bf2f(v[e]);
  }
  const float* wb = dwc_w + (h * kD) * 9;
  const float* bb = dwc_b + h * kD;
#pragma unroll
  for (int d = 0; d < kD; ++d) out[d] += bb[d];
  const int y = n / kHW, x = n % kHW;
#pragma unroll
  for (int ky = 0; ky < 3; ++ky) {
    int yy = y + ky - 1;
    if (yy < 0 || yy >= kHW) continue;
#pragma unroll
    for (int kx = 0; kx < 3; ++kx) {
      int xx = x + kx - 1;
      if (xx < 0 || xx >= kHW) continue;
      const unsigned short* vp = vH_ + (size_t)(yy * kHW + xx) * kD;
#pragma unroll
      for (int d8 = 0; d8 < 4; ++d8) {
        ushort8 vv = *(const ushort8*)(vp + d8 * 8);
#pragma unroll
        for (int e = 0; e < 8; ++e)
          out[d8 * 8 + e] = fmaf(wb[(d8 * 8 + e) * 9 + ky * 3 + kx],
                                 bf2f(vv[e]), out[d8 * 8 + e]);
      }
    }
  }
  unsigned short* qp = qH_ + (size_t)n * kD;
#pragma unroll
  for (int d8 = 0; d8 < 4; ++d8) {
    ushort8 v;
#pragma unroll
    for (int e = 0; e < 8; ++e) v[e] = f2bf(out[d8 * 8 + e]);
    *(ushort8*)(qp + d8 * 8) = v;
  }
}

extern "C" void kernel_launch(void* const* d_in, const int* in_sizes, int n_in,
                              void* d_out, int out_size, void* d_ws, size_t ws_size,
                              hipStream_t stream) {
  const float* x_f     = (const float*)d_in[0];
  const float* x_t     = (const float*)d_in[1];
  const float* Wq      = (const float*)d_in[2];
  const float* Wkv     = (const float*)d_in[3];
  const float* Wproj   = (const float*)d_in[4];
  const float* bproj   = (const float*)d_in[5];
  const float* dwc_w   = (const float*)d_in[6];
  const float* dwc_b   = (const float*)d_in[7];
  const float* an_bias = (const float*)d_in[8];
  const float* na_bias = (const float*)d_in[9];
  const float* ah_bias = (const float*)d_in[10];
  const float* aw_bias = (const float*)d_in[11];
  const float* ha_bias = (const float*)d_in[12];
  const float* wa_bias = (const float*)d_in[13];
  float* out           = (float*)d_out;  // reference output dtype is float32

  const size_t qbiasN = (size_t)kH * kAG * kN;  // elements per table
  const size_t wtE = (size_t)kC * kC + (size_t)kC * kKV + (size_t)kC * kC;
  const size_t tabB = qbiasN * 2 + qbiasN * 4 + wtE * 2;
  if (ws_size < tabB) return;

  const size_t headE = (size_t)kB * kH * kN * kD;   // elements per head-major tensor
  const size_t qFullB   = headE * 2;                // qT bf16 = 25.7MB
  const size_t agentB   = (size_t)kB * kAG * kC * 4;
  const size_t agentvB  = (size_t)kB * kH * kAG * kD * 4;
  const size_t partB    = (size_t)kB * kH * kSEG * kAG * kPART * 4;
  const size_t fullWsB  = tabB + qFullB + agentB + agentvB + partB;  // ~41MB

  char* p = (char*)d_ws;
  unsigned short* qbias = (unsigned short*)p;  p += qbiasN * 2;
  float* abias = (float*)p;                    p += qbiasN * 4;
  unsigned short* WqT   = (unsigned short*)p;  p += (size_t)kC * kC * 2;
  unsigned short* WkvT  = (unsigned short*)p;  p += (size_t)kC * kKV * 2;
  unsigned short* WprojT= (unsigned short*)p;  p += (size_t)kC * kC * 2;

  const int nSetup = kH * kAG + (int)((wtE + 255) / 256);
  setup_kernel<<<nSetup, 256, 0, stream>>>(na_bias, ha_bias, wa_bias,
                                           an_bias, ah_bias, aw_bias,
                                           qbias, abias,
                                           Wq, Wkv, Wproj, WqT, WkvT, WprojT);

  if (ws_size >= fullWsB) {
    // ---------- full-batch: kT/vT in d_out (dead before proj writes out) ----------
    unsigned short* qT = (unsigned short*)p;   p += qFullB;
    float* agent  = (float*)p;                 p += agentB;
    float* agentv = (float*)p;                 p += agentvB;
    float* part   = (float*)p;
    unsigned short* kT = (unsigned short*)d_out;
    unsigned short* vT = kT + headE;

    const int M = kB * kN;
    gemm_qkv_kernel<<<dim3(6, M / BM), 256, 0, stream>>>(
        x_f, x_t, WqT, WkvT, qT, kT, vT, M);
    pool_kernel<<<kB * kAG, 256, 0, stream>>>(qT, agent);
    agent_attn_flash4_kernel<<<kB * kH * kSEG, 256, 0, stream>>>(agent, kT, vT,
                                                                 abias, part);
    agent_merge_kernel<<<kB * kAG, 256, 0, stream>>>(part, agentv);
    qattn_v10_kernel<<<dim3(kNT, kH, kB), 256, 0, stream>>>(
        qT, vT, agent, agentv, qbias, dwc_w, dwc_b);
    gemm_proj_kernel<<<dim3(kC / BN, M / BM), 256, 0, stream>>>(
        qT, WprojT, bproj, out, M);
    return;
  }

  // ---------- fallback: batch-chunked (kT/vT in ws) ----------
  const size_t perbB = (size_t)kH * kN * kD * 2 * 3   // qT + kT + vT (per batch)
                     + ((size_t)kAG * kC + (size_t)kH * kAG * kD
                        + (size_t)kH * kSEG * kAG * kPART) * 4;
  size_t fit = (ws_size - tabB) / perbB;
  int chunk = (int)(fit < 16 ? fit : 16);
  if (chunk < 1) return;

  const size_t headEc = (size_t)chunk * kH * kN * kD;
  unsigned short* qT = (unsigned short*)p;     p += headEc * 2;
  unsigned short* kT = (unsigned short*)p;     p += headEc * 2;
  unsigned short* vT = (unsigned short*)p;     p += headEc * 2;
  float* agent  = (float*)p;                   p += (size_t)chunk * kAG * kC * 4;
  float* agentv = (float*)p;                   p += (size_t)chunk * kH * kAG * kD * 4;
  float* part   = (float*)p;

  for (int b0 = 0; b0 < kB; b0 += chunk) {
    int nb = (kB - b0) < chunk ? (kB - b0) : chunk;
    const int M = nb * kN;
    const float* xf_c = x_f + (size_t)b0 * kN * kC;
    const float* xt_c = x_t + (size_t)b0 * kN * kC;
    float* out_c = out + (size_t)b0 * kN * kC;

    gemm_qkv_kernel<<<dim3(6, M / BM), 256, 0, stream>>>(
        xf_c, xt_c, WqT, WkvT, qT, kT, vT, M);
    pool_kernel<<<nb * kAG, 256, 0, stream>>>(qT, agent);
    agent_attn_flash4_kernel<<<nb * kH * kSEG, 256, 0, stream>>>(agent, kT, vT,
                                                                 abias, part);
    agent_merge_kernel<<<nb * kAG, 256, 0, stream>>>(part, agentv);
    qattn_v10_kernel<<<dim3(kNT, kH, nb), 256, 0, stream>>>(
        qT, vT, agent, agentv, qbias, dwc_w, dwc_b);
    gemm_proj_kernel<<<dim3(kC / BN, M / BM), 256, 0, stream>>>(
        qT, WprojT, bproj, out_c, M);
  }
}